// Round 1
// baseline (488.622 us; speedup 1.0000x reference)
//
#include <hip/hip_runtime.h>
#include <stdint.h>

// DynamicAgentAttention — MI355X gfx950
// B=16, C=512, N=1024 (32x32), HEADS=8, hd=64, AGENT=49 (7x7 pool)
// Pipeline: weights->bf16 | x transpose->bf16 | pool | dw+bn+relu | pw |
//           qkv GEMM (bf16 MFMA) | S1=A.K^T | softmax | agg=P.V | stage2 fused |
//           proj GEMM | mlp1 GEMM | mlp2 GEMM (+residual) -> d_out

typedef float f32x4 __attribute__((ext_vector_type(4)));
typedef short s16x8 __attribute__((ext_vector_type(8)));

__device__ __forceinline__ float bf2f(unsigned short u) {
  union { unsigned int i; float f; } v; v.i = ((unsigned int)u) << 16; return v.f;
}
__device__ __forceinline__ unsigned short f2bf(float f) {
  union { float f; unsigned int i; } v; v.f = f;
  return (unsigned short)((v.i + 0x7FFFu + ((v.i >> 16) & 1u)) >> 16);
}

// ---------------- x [B][C][N] -> xT bf16 [B*N][C] ----------------
__global__ __launch_bounds__(256) void k_transpose(const float* __restrict__ x,
                                                   unsigned short* __restrict__ xT) {
  __shared__ float tile[64][65];
  const int b = blockIdx.z, c0 = blockIdx.y * 64, n0 = blockIdx.x * 64;
  const int t = threadIdx.x, tn = t & 63, tg = t >> 6;
#pragma unroll
  for (int i = 0; i < 16; ++i) {
    const int c_l = tg * 16 + i;
    tile[c_l][tn] = x[(b * 512 + c0 + c_l) * 1024 + n0 + tn];
  }
  __syncthreads();
#pragma unroll
  for (int i = 0; i < 16; ++i) {
    const int n_l = tg * 16 + i;
    xT[(b * 1024 + n0 + n_l) * 512 + c0 + tn] = f2bf(tile[tn][n_l]);
  }
}

// ---------------- weights fp32 -> bf16 (Wqkv = [q_w; kv_w]) ----------------
__global__ __launch_bounds__(256) void k_weights(
    const float* __restrict__ qw, const float* __restrict__ kvw,
    const float* __restrict__ pjw, const float* __restrict__ w1,
    const float* __restrict__ w2, unsigned short* __restrict__ Wqkv,
    unsigned short* __restrict__ Wpj, unsigned short* __restrict__ W1,
    unsigned short* __restrict__ W2) {
  const int u = blockIdx.x * 256 + threadIdx.x;  // float4 unit, total 393216
  const float* s; unsigned short* d; int su, du;
  if (u < 196608) { d = Wqkv; du = u;
    if (u < 65536) { s = qw; su = u; } else { s = kvw; su = u - 65536; } }
  else if (u < 262144) { s = pjw; su = u - 196608; d = Wpj; du = su; }
  else if (u < 327680) { s = w1; su = u - 262144; d = W1; du = su; }
  else { s = w2; su = u - 327680; d = W2; du = su; }
  const f32x4 val = ((const f32x4*)s)[su];
  uint2 pk;
  pk.x = (unsigned)f2bf(val[0]) | ((unsigned)f2bf(val[1]) << 16);
  pk.y = (unsigned)f2bf(val[2]) | ((unsigned)f2bf(val[3]) << 16);
  ((uint2*)d)[du] = pk;
}

// ---------------- adaptive avg pool 32x32 -> 7x7, p[b][c][49] ----------------
__global__ __launch_bounds__(64) void k_pool(const float* __restrict__ x,
                                             float* __restrict__ p) {
  __shared__ float img[1024];
  const int bc = blockIdx.x, t = threadIdx.x;
  const float* src = x + bc * 1024;
#pragma unroll
  for (int i = 0; i < 16; ++i) img[t + 64 * i] = src[t + 64 * i];
  __syncthreads();
  if (t < 49) {
    const int i = t / 7, j = t % 7;
    const int hs = (i * 32) / 7, he = ((i + 1) * 32 + 6) / 7;
    const int ws = (j * 32) / 7, we = ((j + 1) * 32 + 6) / 7;
    float s = 0.f;
    for (int ii = hs; ii < he; ++ii)
      for (int jj = ws; jj < we; ++jj) s += img[ii * 32 + jj];
    p[bc * 49 + t] = s / (float)((he - hs) * (we - ws));
  }
}

// ------- depthwise 3x3 SAME on permuted input + BN + ReLU -> r[b][c][49] -------
__global__ __launch_bounds__(64) void k_dw(
    const float* __restrict__ p, const float* __restrict__ dww,
    const float* __restrict__ dwb, const float* __restrict__ g,
    const float* __restrict__ be, const float* __restrict__ mean,
    const float* __restrict__ var, float* __restrict__ r) {
  const int bc = blockIdx.x, t = threadIdx.x;
  if (t >= 49) return;
  const int b = bc >> 9, c = bc & 511;
  const int i = t / 7, j = t % 7;
  float sum = 0.f;
#pragma unroll
  for (int ki = 0; ki < 3; ++ki)
#pragma unroll
    for (int kj = 0; kj < 3; ++kj) {
      const int ii = i + ki - 1, jj = j + kj - 1;
      if (ii < 0 || ii > 6 || jj < 0 || jj > 6) continue;
      const int f = c * 49 + ii * 7 + jj;  // permuted gather (torch reshape bug kept)
      sum += dww[c * 9 + ki * 3 + kj] * p[(b * 512 + (f & 511)) * 49 + (f >> 9)];
    }
  sum += dwb[c];
  sum = (sum - mean[c]) * rsqrtf(var[c] + 1e-5f) * g[c] + be[c];
  r[bc * 49 + t] = fmaxf(sum, 0.f);
}

// ---------------- pointwise 1x1: A[b][co][49] = pw_w @ r + pw_b ----------------
__global__ __launch_bounds__(256) void k_pw(const float* __restrict__ r,
                                            const float* __restrict__ w,
                                            const float* __restrict__ bias,
                                            float* __restrict__ A) {
  __shared__ float rl[6272];  // 128 ci x 49
  const int b = blockIdx.x >> 3, cg = blockIdx.x & 7;
  const int t = threadIdx.x;
  float acc[13];
#pragma unroll
  for (int i = 0; i < 13; ++i) acc[i] = 0.f;
  for (int ch = 0; ch < 4; ++ch) {
    __syncthreads();
    for (int u = t; u < 6272; u += 256) rl[u] = r[b * 25088 + ch * 6272 + u];
    __syncthreads();
#pragma unroll
    for (int i = 0; i < 13; ++i) {
      const int u = t + 256 * i;
      if (u < 3136) {
        const int col = cg * 64 + u / 49, sI = u % 49;
        const float* wp = w + col * 512 + ch * 128;
        float a = acc[i];
        for (int ci = 0; ci < 128; ++ci) a += wp[ci] * rl[ci * 49 + sI];
        acc[i] = a;
      }
    }
  }
#pragma unroll
  for (int i = 0; i < 13; ++i) {
    const int u = t + 256 * i;
    if (u < 3136) {
      const int col = cg * 64 + u / 49, sI = u % 49;
      A[b * 25088 + col * 49 + sI] = acc[i] + bias[col];
    }
  }
}

// ---------------- bf16 MFMA GEMM: C[M][N] = A[M][512] * B[N][512]^T ----------------
// MODE 0: qkv scatter (N=1536) -> q/k/v bf16 [B][h][n][d]
// MODE 1: proj: +bias -> x_out fp32 + bf16
// MODE 2: mlp1: relu(+bias) -> h1 bf16
// MODE 3: mlp2: +bias +resid -> d_out fp32
template <int MODE>
__global__ __launch_bounds__(256) void k_gemm(
    const unsigned short* __restrict__ A, const unsigned short* __restrict__ B,
    unsigned short* __restrict__ oq, unsigned short* __restrict__ ok,
    unsigned short* __restrict__ ov, float* __restrict__ of,
    unsigned short* __restrict__ obf, const float* __restrict__ bias,
    const float* __restrict__ resid, float* __restrict__ dout) {
  __shared__ unsigned short As[128 * 32];
  __shared__ unsigned short Bs[128 * 32];
  const int t = threadIdx.x;
  const int n0 = blockIdx.x * 128, m0 = blockIdx.y * 128;
  const int w = t >> 6, lane = t & 63;
  const int wr = w >> 1, wc = w & 1, lr = lane & 15, lg = lane >> 4;
  const int row = t >> 2, q = t & 3;
  const unsigned short* gA = A + m0 * 512;
  const unsigned short* gB = B + n0 * 512;

  f32x4 acc[4][4];
#pragma unroll
  for (int mi = 0; mi < 4; ++mi)
#pragma unroll
    for (int ni = 0; ni < 4; ++ni)
#pragma unroll
      for (int rr = 0; rr < 4; ++rr) acc[mi][ni][rr] = 0.f;

  s16x8 ra0 = *(const s16x8*)(gA + row * 512 + q * 8);
  s16x8 ra1 = *(const s16x8*)(gA + (row + 64) * 512 + q * 8);
  s16x8 rb0 = *(const s16x8*)(gB + row * 512 + q * 8);
  s16x8 rb1 = *(const s16x8*)(gB + (row + 64) * 512 + q * 8);

  for (int kt = 0; kt < 16; ++kt) {
    __syncthreads();
    *(s16x8*)(As + row * 32 + q * 8) = ra0;
    *(s16x8*)(As + (row + 64) * 32 + q * 8) = ra1;
    *(s16x8*)(Bs + row * 32 + q * 8) = rb0;
    *(s16x8*)(Bs + (row + 64) * 32 + q * 8) = rb1;
    __syncthreads();
    if (kt < 15) {
      const int ko = (kt + 1) * 32;
      ra0 = *(const s16x8*)(gA + row * 512 + ko + q * 8);
      ra1 = *(const s16x8*)(gA + (row + 64) * 512 + ko + q * 8);
      rb0 = *(const s16x8*)(gB + row * 512 + ko + q * 8);
      rb1 = *(const s16x8*)(gB + (row + 64) * 512 + ko + q * 8);
    }
    s16x8 af[4], bfr[4];
#pragma unroll
    for (int mi = 0; mi < 4; ++mi)
      af[mi] = *(const s16x8*)(As + (wr * 64 + mi * 16 + lr) * 32 + lg * 8);
#pragma unroll
    for (int ni = 0; ni < 4; ++ni)
      bfr[ni] = *(const s16x8*)(Bs + (wc * 64 + ni * 16 + lr) * 32 + lg * 8);
#pragma unroll
    for (int mi = 0; mi < 4; ++mi)
#pragma unroll
      for (int ni = 0; ni < 4; ++ni)
        acc[mi][ni] = __builtin_amdgcn_mfma_f32_16x16x32_bf16(af[mi], bfr[ni],
                                                              acc[mi][ni], 0, 0, 0);
  }

#pragma unroll
  for (int mi = 0; mi < 4; ++mi)
#pragma unroll
    for (int ni = 0; ni < 4; ++ni)
#pragma unroll
      for (int rr = 0; rr < 4; ++rr) {
        const int gm = m0 + wr * 64 + mi * 16 + lg * 4 + rr;
        const int gn = n0 + wc * 64 + ni * 16 + lr;
        const float val = acc[mi][ni][rr];
        if (MODE == 0) {
          const int b = gm >> 10, n = gm & 1023;
          const int hh = (gn >> 6) & 7, dd = gn & 63;
          const int idx = ((b * 8 + hh) * 1024 + n) * 64 + dd;
          const unsigned short bv = f2bf(val);
          if (gn < 512) oq[idx] = bv;
          else if (gn < 1024) ok[idx] = bv;
          else ov[idx] = bv;
        } else if (MODE == 1) {
          const float v2 = val + bias[gn];
          of[gm * 512 + gn] = v2;
          obf[gm * 512 + gn] = f2bf(v2);
        } else if (MODE == 2) {
          const float v2 = fmaxf(val + bias[gn], 0.f);
          obf[gm * 512 + gn] = f2bf(v2);
        } else {
          dout[gm * 512 + gn] = val + bias[gn] + resid[gm * 512 + gn];
        }
      }
}

// ---------------- stage 1 logits: S1[bh][ag][n] = 0.125 * A[ag].k[n] ----------------
__global__ __launch_bounds__(256) void k_attn1(const float* __restrict__ Aag,
                                               const unsigned short* __restrict__ kbf,
                                               float* __restrict__ S1) {
  __shared__ float Al[3136];
  const int blk = blockIdx.x;
  const int nt = blk & 3, h = (blk >> 2) & 7, b = blk >> 5;
  const int t = threadIdx.x;
  const float* Asrc = Aag + b * 25088 + h * 3136;
  for (int u = t; u < 3136; u += 256) Al[u] = Asrc[u];
  __syncthreads();
  const int n = nt * 256 + t;
  const unsigned short* kp = kbf + ((b * 8 + h) * 1024 + n) * 64;
  float kr[64];
#pragma unroll
  for (int i = 0; i < 8; ++i) {
    const s16x8 v = *(const s16x8*)(kp + i * 8);
#pragma unroll
    for (int j = 0; j < 8; ++j) kr[i * 8 + j] = bf2f((unsigned short)v[j]);
  }
  float* srow = S1 + (b * 8 + h) * 49 * 1024 + n;
  for (int ag = 0; ag < 49; ++ag) {
    const float* av = Al + ag * 64;
    float s = 0.f;
#pragma unroll
    for (int d = 0; d < 64; ++d) s += av[d] * kr[d];
    srow[ag * 1024] = s * 0.125f;
  }
}

// ---------------- softmax over n (row length 1024) -> P1 bf16 ----------------
__global__ __launch_bounds__(256) void k_softmax(const float* __restrict__ S1,
                                                 unsigned short* __restrict__ P1) {
  const int row = blockIdx.x, t = threadIdx.x, w = t >> 6;
  const float* s = S1 + row * 1024;
  float v[4], m = -3.0e38f;
#pragma unroll
  for (int i = 0; i < 4; ++i) { v[i] = s[t + 256 * i]; m = fmaxf(m, v[i]); }
#pragma unroll
  for (int o = 1; o < 64; o <<= 1) m = fmaxf(m, __shfl_xor(m, o, 64));
  __shared__ float red[4];
  if ((t & 63) == 0) red[w] = m;
  __syncthreads();
  m = fmaxf(fmaxf(red[0], red[1]), fmaxf(red[2], red[3]));
  float ss = 0.f;
#pragma unroll
  for (int i = 0; i < 4; ++i) { v[i] = __expf(v[i] - m); ss += v[i]; }
  __syncthreads();
#pragma unroll
  for (int o = 1; o < 64; o <<= 1) ss += __shfl_xor(ss, o, 64);
  if ((t & 63) == 0) red[w] = ss;
  __syncthreads();
  ss = red[0] + red[1] + red[2] + red[3];
  const float inv = 1.f / ss;
  unsigned short* prow = P1 + row * 1024;
#pragma unroll
  for (int i = 0; i < 4; ++i) prow[t + 256 * i] = f2bf(v[i] * inv);
}

// ---------------- agg[bh][ag][d] = sum_n P1[ag][n] * v[n][d] ----------------
__global__ __launch_bounds__(256) void k_agg(const unsigned short* __restrict__ P1,
                                             const unsigned short* __restrict__ vbf,
                                             float* __restrict__ agg) {
  __shared__ float vl[8192];   // 128 n x 64 d
  __shared__ float pl[6272];   // 49 ag x 128 n
  const int bh = blockIdx.x, t = threadIdx.x;
  float acc[13];
#pragma unroll
  for (int i = 0; i < 13; ++i) acc[i] = 0.f;
  const unsigned short* vbase = vbf + bh * 65536;
  const unsigned short* pbase = P1 + bh * 50176;
  for (int nt2 = 0; nt2 < 8; ++nt2) {
    __syncthreads();
    for (int u8 = t; u8 < 1024; u8 += 256) {
      const s16x8 v = *(const s16x8*)(vbase + nt2 * 8192 + u8 * 8);
#pragma unroll
      for (int j = 0; j < 8; ++j) vl[u8 * 8 + j] = bf2f((unsigned short)v[j]);
    }
    for (int u8 = t; u8 < 784; u8 += 256) {
      const int ag = u8 >> 4, qq = u8 & 15;
      const s16x8 v = *(const s16x8*)(pbase + ag * 1024 + nt2 * 128 + qq * 8);
#pragma unroll
      for (int j = 0; j < 8; ++j) pl[ag * 128 + qq * 8 + j] = bf2f((unsigned short)v[j]);
    }
    __syncthreads();
#pragma unroll
    for (int i = 0; i < 13; ++i) {
      const int u = t + 256 * i;
      if (u < 3136) {
        const int ag = u >> 6, d = u & 63;
        float a = acc[i];
        for (int nl = 0; nl < 128; ++nl) a += pl[ag * 128 + nl] * vl[nl * 64 + d];
        acc[i] = a;
      }
    }
  }
#pragma unroll
  for (int i = 0; i < 13; ++i) {
    const int u = t + 256 * i;
    if (u < 3136) agg[bh * 3136 + u] = acc[i];
  }
}

// ------- stage 2 fused: logits, softmax(49), enh[n][d] -> enh bf16 [B*N][C] -------
__global__ __launch_bounds__(256) void k_attn2(const float* __restrict__ Aag,
                                               const float* __restrict__ agg,
                                               const unsigned short* __restrict__ qbf,
                                               unsigned short* __restrict__ enh) {
  __shared__ float Al[3136];
  __shared__ float Gl[3136];
  const int blk = blockIdx.x;
  const int nt = blk & 3, h = (blk >> 2) & 7, b = blk >> 5;
  const int t = threadIdx.x, bh = b * 8 + h;
  for (int u = t; u < 3136; u += 256) {
    Al[u] = Aag[b * 25088 + h * 3136 + u];
    Gl[u] = agg[bh * 3136 + u];
  }
  __syncthreads();
  const int n = nt * 256 + t;
  const unsigned short* qp = qbf + (bh * 1024 + n) * 64;
  float qr[64];
#pragma unroll
  for (int i = 0; i < 8; ++i) {
    const s16x8 v = *(const s16x8*)(qp + i * 8);
#pragma unroll
    for (int j = 0; j < 8; ++j) qr[i * 8 + j] = bf2f((unsigned short)v[j]);
  }
  float m = -3.0e38f;
  for (int ag = 0; ag < 49; ++ag) {
    const float* av = Al + ag * 64;
    float s = 0.f;
#pragma unroll
    for (int d = 0; d < 64; ++d) s += av[d] * qr[d];
    m = fmaxf(m, s * 0.125f);
  }
  float accv[64];
#pragma unroll
  for (int d = 0; d < 64; ++d) accv[d] = 0.f;
  float ss = 0.f;
  for (int ag = 0; ag < 49; ++ag) {  // recompute logits (avoids l[49] reg array)
    const float* av = Al + ag * 64;
    float s = 0.f;
#pragma unroll
    for (int d = 0; d < 64; ++d) s += av[d] * qr[d];
    const float p = __expf(s * 0.125f - m);
    ss += p;
    const float* gv = Gl + ag * 64;
#pragma unroll
    for (int d = 0; d < 64; ++d) accv[d] += p * gv[d];
  }
  const float inv = 1.f / ss;
  unsigned short* ep = enh + (b * 1024 + n) * 512 + h * 64;
#pragma unroll
  for (int i = 0; i < 8; ++i) {
    s16x8 pk;
#pragma unroll
    for (int j = 0; j < 8; ++j) pk[j] = (short)f2bf(accv[i * 8 + j] * inv);
    *(s16x8*)(ep + i * 8) = pk;
  }
}

extern "C" void kernel_launch(void* const* d_in, const int* in_sizes, int n_in,
                              void* d_out, int out_size, void* d_ws, size_t ws_size,
                              hipStream_t stream) {
  const float* x    = (const float*)d_in[0];
  const float* q_w  = (const float*)d_in[3];
  const float* kv_w = (const float*)d_in[4];
  const float* dw_w = (const float*)d_in[5];
  const float* dw_b = (const float*)d_in[6];
  const float* bn_g = (const float*)d_in[7];
  const float* bn_b = (const float*)d_in[8];
  const float* bn_m = (const float*)d_in[9];
  const float* bn_v = (const float*)d_in[10];
  const float* pw_w = (const float*)d_in[11];
  const float* pw_b = (const float*)d_in[12];
  const float* pj_w = (const float*)d_in[13];
  const float* pj_b = (const float*)d_in[14];
  const float* e1_w = (const float*)d_in[15];
  const float* e1_b = (const float*)d_in[16];
  const float* e2_w = (const float*)d_in[17];
  const float* e2_b = (const float*)d_in[18];

  char* base = (char*)d_ws;
  size_t off = 0;
  auto alloc = [&](size_t bytes) -> void* {
    void* r = base + off;
    off += (bytes + 255) & ~(size_t)255;
    return r;
  };
  unsigned short* Wqkv = (unsigned short*)alloc(786432ull * 2);
  unsigned short* Wpj  = (unsigned short*)alloc(262144ull * 2);
  unsigned short* W1   = (unsigned short*)alloc(262144ull * 2);
  unsigned short* W2   = (unsigned short*)alloc(262144ull * 2);
  unsigned short* xT   = (unsigned short*)alloc(8388608ull * 2);
  unsigned short* qb   = (unsigned short*)alloc(8388608ull * 2);
  unsigned short* kb   = (unsigned short*)alloc(8388608ull * 2);
  unsigned short* vb   = (unsigned short*)alloc(8388608ull * 2);
  float* pbuf = (float*)alloc(401408ull * 4);
  float* rbuf = (float*)alloc(401408ull * 4);
  float* Abuf = (float*)alloc(401408ull * 4);
  float* S1   = (float*)alloc(6422528ull * 4);
  unsigned short* P1 = (unsigned short*)alloc(6422528ull * 2);
  float* aggb = (float*)alloc(401408ull * 4);
  unsigned short* enh  = (unsigned short*)alloc(8388608ull * 2);
  float* xout = (float*)alloc(8388608ull * 4);
  unsigned short* xoutb = (unsigned short*)alloc(8388608ull * 2);
  unsigned short* h1    = (unsigned short*)alloc(8388608ull * 2);
  (void)ws_size; (void)in_sizes; (void)n_in; (void)out_size;

  k_weights<<<1536, 256, 0, stream>>>(q_w, kv_w, pj_w, e1_w, e2_w, Wqkv, Wpj, W1, W2);
  k_transpose<<<dim3(16, 8, 16), 256, 0, stream>>>(x, xT);
  k_pool<<<8192, 64, 0, stream>>>(x, pbuf);
  k_dw<<<8192, 64, 0, stream>>>(pbuf, dw_w, dw_b, bn_g, bn_b, bn_m, bn_v, rbuf);
  k_pw<<<128, 256, 0, stream>>>(rbuf, pw_w, pw_b, Abuf);
  k_gemm<0><<<dim3(12, 128), 256, 0, stream>>>(xT, Wqkv, qb, kb, vb,
                                               nullptr, nullptr, nullptr, nullptr, nullptr);
  k_attn1<<<512, 256, 0, stream>>>(Abuf, kb, S1);
  k_softmax<<<6272, 256, 0, stream>>>(S1, P1);
  k_agg<<<128, 256, 0, stream>>>(P1, vb, aggb);
  k_attn2<<<512, 256, 0, stream>>>(Abuf, aggb, qb, enh);
  k_gemm<1><<<dim3(4, 128), 256, 0, stream>>>(enh, Wpj, nullptr, nullptr, nullptr,
                                              xout, xoutb, pj_b, nullptr, nullptr);
  k_gemm<2><<<dim3(4, 128), 256, 0, stream>>>(xoutb, W1, nullptr, nullptr, nullptr,
                                              nullptr, h1, e1_b, nullptr, nullptr);
  k_gemm<3><<<dim3(4, 128), 256, 0, stream>>>(h1, W2, nullptr, nullptr, nullptr,
                                              nullptr, nullptr, e2_b, xout, (float*)d_out);
}

// Round 2
// 290.552 us; speedup vs baseline: 1.6817x; 1.6817x over previous
//
#include <hip/hip_runtime.h>
#include <stdint.h>

// DynamicAgentAttention — MI355X gfx950
// B=16, C=512, N=1024 (32x32), HEADS=8, hd=64, AGENT=49 (7x7 pool)

typedef float f32x4 __attribute__((ext_vector_type(4)));
typedef short s16x8 __attribute__((ext_vector_type(8)));

__device__ __forceinline__ float bf2f(unsigned short u) {
  union { unsigned int i; float f; } v; v.i = ((unsigned int)u) << 16; return v.f;
}
__device__ __forceinline__ unsigned short f2bf(float f) {
  union { float f; unsigned int i; } v; v.f = f;
  return (unsigned short)((v.i + 0x7FFFu + ((v.i >> 16) & 1u)) >> 16);
}

// ---------------- x [B][C][N] -> xT bf16 [B*N][C] ----------------
__global__ __launch_bounds__(256) void k_transpose(const float* __restrict__ x,
                                                   unsigned short* __restrict__ xT) {
  __shared__ float tile[64][65];
  const int b = blockIdx.z, c0 = blockIdx.y * 64, n0 = blockIdx.x * 64;
  const int t = threadIdx.x, tn = t & 63, tg = t >> 6;
#pragma unroll
  for (int i = 0; i < 16; ++i) {
    const int c_l = tg * 16 + i;
    tile[c_l][tn] = x[(b * 512 + c0 + c_l) * 1024 + n0 + tn];
  }
  __syncthreads();
#pragma unroll
  for (int i = 0; i < 16; ++i) {
    const int n_l = tg * 16 + i;
    xT[(b * 1024 + n0 + n_l) * 512 + c0 + tn] = f2bf(tile[tn][n_l]);
  }
}

// ---------------- weights fp32 -> bf16 (Wqkv = [q_w; kv_w]) ----------------
__global__ __launch_bounds__(256) void k_weights(
    const float* __restrict__ qw, const float* __restrict__ kvw,
    const float* __restrict__ pjw, const float* __restrict__ w1,
    const float* __restrict__ w2, unsigned short* __restrict__ Wqkv,
    unsigned short* __restrict__ Wpj, unsigned short* __restrict__ W1,
    unsigned short* __restrict__ W2) {
  const int u = blockIdx.x * 256 + threadIdx.x;  // float4 unit, total 393216
  const float* s; unsigned short* d; int su, du;
  if (u < 196608) { d = Wqkv; du = u;
    if (u < 65536) { s = qw; su = u; } else { s = kvw; su = u - 65536; } }
  else if (u < 262144) { s = pjw; su = u - 196608; d = Wpj; du = su; }
  else if (u < 327680) { s = w1; su = u - 262144; d = W1; du = su; }
  else { s = w2; su = u - 327680; d = W2; du = su; }
  const f32x4 val = ((const f32x4*)s)[su];
  uint2 pk;
  pk.x = (unsigned)f2bf(val[0]) | ((unsigned)f2bf(val[1]) << 16);
  pk.y = (unsigned)f2bf(val[2]) | ((unsigned)f2bf(val[3]) << 16);
  ((uint2*)d)[du] = pk;
}

// ---------------- adaptive avg pool 32x32 -> 7x7, p[b][c][49] ----------------
__global__ __launch_bounds__(64) void k_pool(const float* __restrict__ x,
                                             float* __restrict__ p) {
  __shared__ float img[1024];
  const int bc = blockIdx.x, t = threadIdx.x;
  const float* src = x + bc * 1024;
#pragma unroll
  for (int i = 0; i < 16; ++i) img[t + 64 * i] = src[t + 64 * i];
  __syncthreads();
  if (t < 49) {
    const int i = t / 7, j = t % 7;
    const int hs = (i * 32) / 7, he = ((i + 1) * 32 + 6) / 7;
    const int ws = (j * 32) / 7, we = ((j + 1) * 32 + 6) / 7;
    float s = 0.f;
    for (int ii = hs; ii < he; ++ii)
      for (int jj = ws; jj < we; ++jj) s += img[ii * 32 + jj];
    p[bc * 49 + t] = s / (float)((he - hs) * (we - ws));
  }
}

// ------- depthwise 3x3 SAME on permuted input + BN + ReLU -> r[b][c][49] -------
__global__ __launch_bounds__(64) void k_dw(
    const float* __restrict__ p, const float* __restrict__ dww,
    const float* __restrict__ dwb, const float* __restrict__ g,
    const float* __restrict__ be, const float* __restrict__ mean,
    const float* __restrict__ var, float* __restrict__ r) {
  const int bc = blockIdx.x, t = threadIdx.x;
  if (t >= 49) return;
  const int b = bc >> 9, c = bc & 511;
  const int i = t / 7, j = t % 7;
  float sum = 0.f;
#pragma unroll
  for (int ki = 0; ki < 3; ++ki)
#pragma unroll
    for (int kj = 0; kj < 3; ++kj) {
      const int ii = i + ki - 1, jj = j + kj - 1;
      if (ii < 0 || ii > 6 || jj < 0 || jj > 6) continue;
      const int f = c * 49 + ii * 7 + jj;  // permuted gather (torch reshape bug kept)
      sum += dww[c * 9 + ki * 3 + kj] * p[(b * 512 + (f & 511)) * 49 + (f >> 9)];
    }
  sum += dwb[c];
  sum = (sum - mean[c]) * rsqrtf(var[c] + 1e-5f) * g[c] + be[c];
  r[bc * 49 + t] = fmaxf(sum, 0.f);
}

// ------- pointwise 1x1 as LDS-staged GEMM: A[b][co][49] = pw_w @ r + pw_b -------
// grid = 256 blocks (16 b x 16 cg of 32 cols). wave = 8-col group, lane = s.
__global__ __launch_bounds__(256) void k_pw(const float* __restrict__ r,
                                            const float* __restrict__ w,
                                            const float* __restrict__ bias,
                                            float* __restrict__ A) {
  __shared__ float wl[128 * 36];  // [ci][co(32) pad 36] -> 16B-aligned rows
  __shared__ float rl[128 * 64];  // [ci][s(49) pad 64]
  const int blk = blockIdx.x;
  const int b = blk >> 4, cg = blk & 15;
  const int t = threadIdx.x, wv = t >> 6, lane = t & 63;
  float acc[8];
#pragma unroll
  for (int j = 0; j < 8; ++j) acc[j] = 0.f;
  for (int ch = 0; ch < 4; ++ch) {
    __syncthreads();
#pragma unroll
    for (int u = t; u < 4096; u += 256) {  // w chunk: 32 co x 128 ci
      const int co = u >> 7, ci = u & 127;
      wl[ci * 36 + co] = w[(cg * 32 + co) * 512 + ch * 128 + ci];
    }
    for (int u = t; u < 6272; u += 256) {  // r chunk: 128 ci x 49 s
      const int ci = u / 49, s = u % 49;
      rl[ci * 64 + s] = r[b * 25088 + ch * 6272 + u];
    }
    __syncthreads();
#pragma unroll 4
    for (int ci = 0; ci < 128; ++ci) {
      const f32x4 w0 = *(const f32x4*)(wl + ci * 36 + wv * 8);      // broadcast
      const f32x4 w1 = *(const f32x4*)(wl + ci * 36 + wv * 8 + 4);  // broadcast
      const float rv = rl[ci * 64 + lane];
#pragma unroll
      for (int j = 0; j < 4; ++j) { acc[j] += w0[j] * rv; acc[4 + j] += w1[j] * rv; }
    }
  }
  if (lane < 49) {
#pragma unroll
    for (int j = 0; j < 8; ++j) {
      const int co = cg * 32 + wv * 8 + j;
      A[b * 25088 + co * 49 + lane] = acc[j] + bias[co];
    }
  }
}

// ---------------- bf16 MFMA GEMM: C[M][N] = A[M][512] * B[N][512]^T ----------------
template <int MODE>
__global__ __launch_bounds__(256) void k_gemm(
    const unsigned short* __restrict__ A, const unsigned short* __restrict__ B,
    unsigned short* __restrict__ oq, unsigned short* __restrict__ ok,
    unsigned short* __restrict__ ov, float* __restrict__ of,
    unsigned short* __restrict__ obf, const float* __restrict__ bias,
    const float* __restrict__ resid, float* __restrict__ dout) {
  __shared__ unsigned short As[128 * 32];
  __shared__ unsigned short Bs[128 * 32];
  const int t = threadIdx.x;
  const int n0 = blockIdx.x * 128, m0 = blockIdx.y * 128;
  const int w = t >> 6, lane = t & 63;
  const int wr = w >> 1, wc = w & 1, lr = lane & 15, lg = lane >> 4;
  const int row = t >> 2, q = t & 3;
  const unsigned short* gA = A + m0 * 512;
  const unsigned short* gB = B + n0 * 512;

  f32x4 acc[4][4];
#pragma unroll
  for (int mi = 0; mi < 4; ++mi)
#pragma unroll
    for (int ni = 0; ni < 4; ++ni)
#pragma unroll
      for (int rr = 0; rr < 4; ++rr) acc[mi][ni][rr] = 0.f;

  s16x8 ra0 = *(const s16x8*)(gA + row * 512 + q * 8);
  s16x8 ra1 = *(const s16x8*)(gA + (row + 64) * 512 + q * 8);
  s16x8 rb0 = *(const s16x8*)(gB + row * 512 + q * 8);
  s16x8 rb1 = *(const s16x8*)(gB + (row + 64) * 512 + q * 8);

  for (int kt = 0; kt < 16; ++kt) {
    __syncthreads();
    *(s16x8*)(As + row * 32 + q * 8) = ra0;
    *(s16x8*)(As + (row + 64) * 32 + q * 8) = ra1;
    *(s16x8*)(Bs + row * 32 + q * 8) = rb0;
    *(s16x8*)(Bs + (row + 64) * 32 + q * 8) = rb1;
    __syncthreads();
    if (kt < 15) {
      const int ko = (kt + 1) * 32;
      ra0 = *(const s16x8*)(gA + row * 512 + ko + q * 8);
      ra1 = *(const s16x8*)(gA + (row + 64) * 512 + ko + q * 8);
      rb0 = *(const s16x8*)(gB + row * 512 + ko + q * 8);
      rb1 = *(const s16x8*)(gB + (row + 64) * 512 + ko + q * 8);
    }
    s16x8 af[4], bfr[4];
#pragma unroll
    for (int mi = 0; mi < 4; ++mi)
      af[mi] = *(const s16x8*)(As + (wr * 64 + mi * 16 + lr) * 32 + lg * 8);
#pragma unroll
    for (int ni = 0; ni < 4; ++ni)
      bfr[ni] = *(const s16x8*)(Bs + (wc * 64 + ni * 16 + lr) * 32 + lg * 8);
#pragma unroll
    for (int mi = 0; mi < 4; ++mi)
#pragma unroll
      for (int ni = 0; ni < 4; ++ni)
        acc[mi][ni] = __builtin_amdgcn_mfma_f32_16x16x32_bf16(af[mi], bfr[ni],
                                                              acc[mi][ni], 0, 0, 0);
  }

#pragma unroll
  for (int mi = 0; mi < 4; ++mi)
#pragma unroll
    for (int ni = 0; ni < 4; ++ni)
#pragma unroll
      for (int rr = 0; rr < 4; ++rr) {
        const int gm = m0 + wr * 64 + mi * 16 + lg * 4 + rr;
        const int gn = n0 + wc * 64 + ni * 16 + lr;
        const float val = acc[mi][ni][rr];
        if (MODE == 0) {
          const int b = gm >> 10, n = gm & 1023;
          const int hh = (gn >> 6) & 7, dd = gn & 63;
          const int idx = ((b * 8 + hh) * 1024 + n) * 64 + dd;
          const unsigned short bv = f2bf(val);
          if (gn < 512) oq[idx] = bv;
          else if (gn < 1024) ok[idx] = bv;
          else ov[idx] = bv;
        } else if (MODE == 1) {
          const float v2 = val + bias[gn];
          of[gm * 512 + gn] = v2;
          obf[gm * 512 + gn] = f2bf(v2);
        } else if (MODE == 2) {
          const float v2 = fmaxf(val + bias[gn], 0.f);
          obf[gm * 512 + gn] = f2bf(v2);
        } else {
          dout[gm * 512 + gn] = val + bias[gn] + resid[gm * 512 + gn];
        }
      }
}

// ---------------- stage 1 logits: S1[bh][ag][n] = 0.125 * A[ag].k[n] ----------------
__global__ __launch_bounds__(256) void k_attn1(const float* __restrict__ Aag,
                                               const unsigned short* __restrict__ kbf,
                                               float* __restrict__ S1) {
  __shared__ float Al[3136];
  const int blk = blockIdx.x;
  const int nt = blk & 3, h = (blk >> 2) & 7, b = blk >> 5;
  const int t = threadIdx.x;
  const float* Asrc = Aag + b * 25088 + h * 3136;
  for (int u = t; u < 3136; u += 256) Al[u] = Asrc[u];
  __syncthreads();
  const int n = nt * 256 + t;
  const unsigned short* kp = kbf + ((b * 8 + h) * 1024 + n) * 64;
  float kr[64];
#pragma unroll
  for (int i = 0; i < 8; ++i) {
    const s16x8 v = *(const s16x8*)(kp + i * 8);
#pragma unroll
    for (int j = 0; j < 8; ++j) kr[i * 8 + j] = bf2f((unsigned short)v[j]);
  }
  float* srow = S1 + (b * 8 + h) * 49 * 1024 + n;
  for (int ag = 0; ag < 49; ++ag) {
    float s0 = 0.f, s1 = 0.f, s2 = 0.f, s3 = 0.f;
#pragma unroll
    for (int dq = 0; dq < 16; ++dq) {
      const f32x4 a4 = *(const f32x4*)(Al + ag * 64 + dq * 4);  // broadcast
      s0 += a4[0] * kr[dq * 4 + 0]; s1 += a4[1] * kr[dq * 4 + 1];
      s2 += a4[2] * kr[dq * 4 + 2]; s3 += a4[3] * kr[dq * 4 + 3];
    }
    srow[ag * 1024] = (s0 + s1 + s2 + s3) * 0.125f;
  }
}

// ---------------- softmax over n (row length 1024) -> P1 bf16 ----------------
__global__ __launch_bounds__(256) void k_softmax(const float* __restrict__ S1,
                                                 unsigned short* __restrict__ P1) {
  const int row = blockIdx.x, t = threadIdx.x, w = t >> 6;
  const float* s = S1 + row * 1024;
  float v[4], m = -3.0e38f;
#pragma unroll
  for (int i = 0; i < 4; ++i) { v[i] = s[t + 256 * i]; m = fmaxf(m, v[i]); }
#pragma unroll
  for (int o = 1; o < 64; o <<= 1) m = fmaxf(m, __shfl_xor(m, o, 64));
  __shared__ float red[4];
  if ((t & 63) == 0) red[w] = m;
  __syncthreads();
  m = fmaxf(fmaxf(red[0], red[1]), fmaxf(red[2], red[3]));
  float ss = 0.f;
#pragma unroll
  for (int i = 0; i < 4; ++i) { v[i] = __expf(v[i] - m); ss += v[i]; }
  __syncthreads();
#pragma unroll
  for (int o = 1; o < 64; o <<= 1) ss += __shfl_xor(ss, o, 64);
  if ((t & 63) == 0) red[w] = ss;
  __syncthreads();
  ss = red[0] + red[1] + red[2] + red[3];
  const float inv = 1.f / ss;
  unsigned short* prow = P1 + row * 1024;
#pragma unroll
  for (int i = 0; i < 4; ++i) prow[t + 256 * i] = f2bf(v[i] * inv);
}

// ------- agg partials: aggp[ks][bh][ag][d] = sum_{n in ks-range} P1[ag][n] v[n][d] -------
// grid 512 = 128 bh x 4 ksplit. wave = 16-d group, lane = ag (49 valid).
__global__ __launch_bounds__(256) void k_agg(const unsigned short* __restrict__ P1,
                                             const unsigned short* __restrict__ vbf,
                                             float* __restrict__ aggp) {
  __shared__ float vl[128 * 64];  // [n][d] 32KB
  __shared__ float pl[128 * 52];  // [n][ag pad 52] 26KB
  const int blk = blockIdx.x;
  const int bh = blk >> 2, ks = blk & 3;
  const int t = threadIdx.x, wv = t >> 6, lane = t & 63;
  float acc[16];
#pragma unroll
  for (int j = 0; j < 16; ++j) acc[j] = 0.f;
  const unsigned short* vbase = vbf + bh * 65536 + ks * 256 * 64;
  const unsigned short* pbase = P1 + bh * 50176 + ks * 256;
  for (int nc = 0; nc < 2; ++nc) {
    __syncthreads();
#pragma unroll
    for (int u8 = t; u8 < 1024; u8 += 256) {  // v: 128 n x 64 d
      const s16x8 v = *(const s16x8*)(vbase + nc * 8192 + u8 * 8);
#pragma unroll
      for (int j = 0; j < 8; ++j) vl[u8 * 8 + j] = bf2f((unsigned short)v[j]);
    }
    for (int u = t; u < 6272; u += 256) {  // p: 49 ag x 128 n, transposed store
      const int ag = u >> 7, n = u & 127;
      pl[n * 52 + ag] = bf2f(P1[0] * 0 + pbase[ag * 1024 + nc * 128 + n]) ;
    }
    __syncthreads();
#pragma unroll 2
    for (int n = 0; n < 128; ++n) {
      const float pv = pl[n * 52 + lane];
      const f32x4 v0 = *(const f32x4*)(vl + n * 64 + wv * 16);       // broadcast
      const f32x4 v1 = *(const f32x4*)(vl + n * 64 + wv * 16 + 4);
      const f32x4 v2 = *(const f32x4*)(vl + n * 64 + wv * 16 + 8);
      const f32x4 v3 = *(const f32x4*)(vl + n * 64 + wv * 16 + 12);
#pragma unroll
      for (int j = 0; j < 4; ++j) {
        acc[j] += pv * v0[j]; acc[4 + j] += pv * v1[j];
        acc[8 + j] += pv * v2[j]; acc[12 + j] += pv * v3[j];
      }
    }
  }
  // LDS transpose for coalesced global write (pad 68 to spread banks)
  __syncthreads();
  if (lane < 49) {
#pragma unroll
    for (int j = 0; j < 16; ++j) vl[lane * 68 + wv * 16 + j] = acc[j];
  }
  __syncthreads();
  float* out = aggp + (ks * 128 + bh) * 3136;
  for (int u = t; u < 3136; u += 256) out[u] = vl[(u >> 6) * 68 + (u & 63)];
}

// ------- stage 2 fused (no max pass; logits ~ +-0.2): enh bf16 [B*N][C] -------
__global__ __launch_bounds__(256) void k_attn2(const float* __restrict__ Aag,
                                               const float* __restrict__ aggp,
                                               const unsigned short* __restrict__ qbf,
                                               unsigned short* __restrict__ enh) {
  __shared__ float Al[3136];
  __shared__ float Gl[3136];
  const int blk = blockIdx.x;
  const int nt = blk & 3, h = (blk >> 2) & 7, b = blk >> 5;
  const int t = threadIdx.x, bh = b * 8 + h;
  for (int u = t; u < 3136; u += 256) {
    Al[u] = Aag[b * 25088 + h * 3136 + u];
    Gl[u] = aggp[bh * 3136 + u] + aggp[(128 + bh) * 3136 + u] +
            aggp[(256 + bh) * 3136 + u] + aggp[(384 + bh) * 3136 + u];
  }
  __syncthreads();
  const int n = nt * 256 + t;
  const unsigned short* qp = qbf + (bh * 1024 + n) * 64;
  float qr[64];
#pragma unroll
  for (int i = 0; i < 8; ++i) {
    const s16x8 v = *(const s16x8*)(qp + i * 8);
#pragma unroll
    for (int j = 0; j < 8; ++j) qr[i * 8 + j] = bf2f((unsigned short)v[j]);
  }
  float accv[64];
#pragma unroll
  for (int d = 0; d < 64; ++d) accv[d] = 0.f;
  float ss = 0.f;
  for (int ag = 0; ag < 49; ++ag) {
    float s0 = 0.f, s1 = 0.f, s2 = 0.f, s3 = 0.f;
#pragma unroll
    for (int dq = 0; dq < 16; ++dq) {
      const f32x4 a4 = *(const f32x4*)(Al + ag * 64 + dq * 4);  // broadcast
      s0 += a4[0] * qr[dq * 4 + 0]; s1 += a4[1] * qr[dq * 4 + 1];
      s2 += a4[2] * qr[dq * 4 + 2]; s3 += a4[3] * qr[dq * 4 + 3];
    }
    const float p = __expf((s0 + s1 + s2 + s3) * 0.125f);
    ss += p;
#pragma unroll
    for (int dq = 0; dq < 16; ++dq) {
      const f32x4 g4 = *(const f32x4*)(Gl + ag * 64 + dq * 4);  // broadcast
#pragma unroll
      for (int j = 0; j < 4; ++j) accv[dq * 4 + j] += p * g4[j];
    }
  }
  const float inv = 1.f / ss;
  unsigned short* ep = enh + (b * 1024 + n) * 512 + h * 64;
#pragma unroll
  for (int i = 0; i < 8; ++i) {
    s16x8 pk;
#pragma unroll
    for (int j = 0; j < 8; ++j) pk[j] = (short)f2bf(accv[i * 8 + j] * inv);
    *(s16x8*)(ep + i * 8) = pk;
  }
}

extern "C" void kernel_launch(void* const* d_in, const int* in_sizes, int n_in,
                              void* d_out, int out_size, void* d_ws, size_t ws_size,
                              hipStream_t stream) {
  const float* x    = (const float*)d_in[0];
  const float* q_w  = (const float*)d_in[3];
  const float* kv_w = (const float*)d_in[4];
  const float* dw_w = (const float*)d_in[5];
  const float* dw_b = (const float*)d_in[6];
  const float* bn_g = (const float*)d_in[7];
  const float* bn_b = (const float*)d_in[8];
  const float* bn_m = (const float*)d_in[9];
  const float* bn_v = (const float*)d_in[10];
  const float* pw_w = (const float*)d_in[11];
  const float* pw_b = (const float*)d_in[12];
  const float* pj_w = (const float*)d_in[13];
  const float* pj_b = (const float*)d_in[14];
  const float* e1_w = (const float*)d_in[15];
  const float* e1_b = (const float*)d_in[16];
  const float* e2_w = (const float*)d_in[17];
  const float* e2_b = (const float*)d_in[18];

  char* base = (char*)d_ws;
  size_t off = 0;
  auto alloc = [&](size_t bytes) -> void* {
    void* r = base + off;
    off += (bytes + 255) & ~(size_t)255;
    return r;
  };
  unsigned short* Wqkv = (unsigned short*)alloc(786432ull * 2);
  unsigned short* Wpj  = (unsigned short*)alloc(262144ull * 2);
  unsigned short* W1   = (unsigned short*)alloc(262144ull * 2);
  unsigned short* W2   = (unsigned short*)alloc(262144ull * 2);
  unsigned short* xT   = (unsigned short*)alloc(8388608ull * 2);
  unsigned short* qb   = (unsigned short*)alloc(8388608ull * 2);
  unsigned short* kb   = (unsigned short*)alloc(8388608ull * 2);
  unsigned short* vb   = (unsigned short*)alloc(8388608ull * 2);
  float* pbuf = (float*)alloc(401408ull * 4);
  float* rbuf = (float*)alloc(401408ull * 4);
  float* Abuf = (float*)alloc(401408ull * 4);
  float* S1   = (float*)alloc(6422528ull * 4);
  unsigned short* P1 = (unsigned short*)alloc(6422528ull * 2);
  float* aggp = (float*)alloc(1605632ull * 4);
  unsigned short* enh  = (unsigned short*)alloc(8388608ull * 2);
  float* xout = (float*)alloc(8388608ull * 4);
  unsigned short* xoutb = (unsigned short*)alloc(8388608ull * 2);
  unsigned short* h1    = (unsigned short*)alloc(8388608ull * 2);
  (void)ws_size; (void)in_sizes; (void)n_in; (void)out_size;

  k_weights<<<1536, 256, 0, stream>>>(q_w, kv_w, pj_w, e1_w, e2_w, Wqkv, Wpj, W1, W2);
  k_transpose<<<dim3(16, 8, 16), 256, 0, stream>>>(x, xT);
  k_pool<<<8192, 64, 0, stream>>>(x, pbuf);
  k_dw<<<8192, 64, 0, stream>>>(pbuf, dw_w, dw_b, bn_g, bn_b, bn_m, bn_v, rbuf);
  k_pw<<<256, 256, 0, stream>>>(rbuf, pw_w, pw_b, Abuf);
  k_gemm<0><<<dim3(12, 128), 256, 0, stream>>>(xT, Wqkv, qb, kb, vb,
                                               nullptr, nullptr, nullptr, nullptr, nullptr);
  k_attn1<<<512, 256, 0, stream>>>(Abuf, kb, S1);
  k_softmax<<<6272, 256, 0, stream>>>(S1, P1);
  k_agg<<<512, 256, 0, stream>>>(P1, vb, aggp);
  k_attn2<<<512, 256, 0, stream>>>(Abuf, aggp, qb, enh);
  k_gemm<1><<<dim3(4, 128), 256, 0, stream>>>(enh, Wpj, nullptr, nullptr, nullptr,
                                              xout, xoutb, pj_b, nullptr, nullptr);
  k_gemm<2><<<dim3(4, 128), 256, 0, stream>>>(xoutb, W1, nullptr, nullptr, nullptr,
                                              nullptr, h1, e1_b, nullptr, nullptr);
  k_gemm<3><<<dim3(4, 128), 256, 0, stream>>>(h1, W2, nullptr, nullptr, nullptr,
                                              nullptr, nullptr, e2_b, xout, (float*)d_out);
}

// Round 3
// 269.966 us; speedup vs baseline: 1.8099x; 1.0763x over previous
//
#include <hip/hip_runtime.h>
#include <stdint.h>

// DynamicAgentAttention — MI355X gfx950
// B=16, C=512, N=1024 (32x32), HEADS=8, hd=64, AGENT=49 (7x7 pool)

typedef float f32x4 __attribute__((ext_vector_type(4)));
typedef short s16x8 __attribute__((ext_vector_type(8)));

typedef __attribute__((address_space(1))) void glob_v;
typedef __attribute__((address_space(3))) void lds_v;
#define GLD16(g, l) \
  __builtin_amdgcn_global_load_lds((glob_v*)(g), (lds_v*)(l), 16, 0, 0)

__device__ __forceinline__ float bf2f(unsigned short u) {
  union { unsigned int i; float f; } v; v.i = ((unsigned int)u) << 16; return v.f;
}
__device__ __forceinline__ unsigned short f2bf(float f) {
  union { float f; unsigned int i; } v; v.f = f;
  return (unsigned short)((v.i + 0x7FFFu + ((v.i >> 16) & 1u)) >> 16);
}

// ---------------- x [B][C][N] -> xT bf16 [B*N][C] ----------------
__global__ __launch_bounds__(256) void k_transpose(const float* __restrict__ x,
                                                   unsigned short* __restrict__ xT) {
  __shared__ float tile[64][65];
  const int b = blockIdx.z, c0 = blockIdx.y * 64, n0 = blockIdx.x * 64;
  const int t = threadIdx.x, tn = t & 63, tg = t >> 6;
#pragma unroll
  for (int i = 0; i < 16; ++i) {
    const int c_l = tg * 16 + i;
    tile[c_l][tn] = x[(b * 512 + c0 + c_l) * 1024 + n0 + tn];
  }
  __syncthreads();
#pragma unroll
  for (int i = 0; i < 16; ++i) {
    const int n_l = tg * 16 + i;
    xT[(b * 1024 + n0 + n_l) * 512 + c0 + tn] = f2bf(tile[tn][n_l]);
  }
}

// ---------------- weights fp32 -> bf16 (Wqkv = [q_w; kv_w]) ----------------
__global__ __launch_bounds__(256) void k_weights(
    const float* __restrict__ qw, const float* __restrict__ kvw,
    const float* __restrict__ pjw, const float* __restrict__ w1,
    const float* __restrict__ w2, unsigned short* __restrict__ Wqkv,
    unsigned short* __restrict__ Wpj, unsigned short* __restrict__ W1,
    unsigned short* __restrict__ W2) {
  const int u = blockIdx.x * 256 + threadIdx.x;  // float4 unit, total 393216
  const float* s; unsigned short* d; int su, du;
  if (u < 196608) { d = Wqkv; du = u;
    if (u < 65536) { s = qw; su = u; } else { s = kvw; su = u - 65536; } }
  else if (u < 262144) { s = pjw; su = u - 196608; d = Wpj; du = su; }
  else if (u < 327680) { s = w1; su = u - 262144; d = W1; du = su; }
  else { s = w2; su = u - 327680; d = W2; du = su; }
  const f32x4 val = ((const f32x4*)s)[su];
  uint2 pk;
  pk.x = (unsigned)f2bf(val[0]) | ((unsigned)f2bf(val[1]) << 16);
  pk.y = (unsigned)f2bf(val[2]) | ((unsigned)f2bf(val[3]) << 16);
  ((uint2*)d)[du] = pk;
}

// ---------------- adaptive avg pool 32x32 -> 7x7, p[b][c][49] ----------------
__global__ __launch_bounds__(64) void k_pool(const float* __restrict__ x,
                                             float* __restrict__ p) {
  __shared__ float img[1024];
  const int bc = blockIdx.x, t = threadIdx.x;
  const float* src = x + bc * 1024;
#pragma unroll
  for (int i = 0; i < 16; ++i) img[t + 64 * i] = src[t + 64 * i];
  __syncthreads();
  if (t < 49) {
    const int i = t / 7, j = t % 7;
    const int hs = (i * 32) / 7, he = ((i + 1) * 32 + 6) / 7;
    const int ws = (j * 32) / 7, we = ((j + 1) * 32 + 6) / 7;
    float s = 0.f;
    for (int ii = hs; ii < he; ++ii)
      for (int jj = ws; jj < we; ++jj) s += img[ii * 32 + jj];
    p[bc * 49 + t] = s / (float)((he - hs) * (we - ws));
  }
}

// ------- depthwise 3x3 SAME on permuted input + BN + ReLU -> r[b][c][49] -------
__global__ __launch_bounds__(64) void k_dw(
    const float* __restrict__ p, const float* __restrict__ dww,
    const float* __restrict__ dwb, const float* __restrict__ g,
    const float* __restrict__ be, const float* __restrict__ mean,
    const float* __restrict__ var, float* __restrict__ r) {
  const int bc = blockIdx.x, t = threadIdx.x;
  if (t >= 49) return;
  const int b = bc >> 9, c = bc & 511;
  const int i = t / 7, j = t % 7;
  float sum = 0.f;
#pragma unroll
  for (int ki = 0; ki < 3; ++ki)
#pragma unroll
    for (int kj = 0; kj < 3; ++kj) {
      const int ii = i + ki - 1, jj = j + kj - 1;
      if (ii < 0 || ii > 6 || jj < 0 || jj > 6) continue;
      const int f = c * 49 + ii * 7 + jj;  // permuted gather (torch reshape bug kept)
      sum += dww[c * 9 + ki * 3 + kj] * p[(b * 512 + (f & 511)) * 49 + (f >> 9)];
    }
  sum += dwb[c];
  sum = (sum - mean[c]) * rsqrtf(var[c] + 1e-5f) * g[c] + be[c];
  r[bc * 49 + t] = fmaxf(sum, 0.f);
}

// ------- pointwise 1x1 as LDS-staged GEMM: A[b][co][49] = pw_w @ r + pw_b -------
__global__ __launch_bounds__(256) void k_pw(const float* __restrict__ r,
                                            const float* __restrict__ w,
                                            const float* __restrict__ bias,
                                            float* __restrict__ A) {
  __shared__ float wl[128 * 36];
  __shared__ float rl[128 * 64];
  const int blk = blockIdx.x;
  const int b = blk >> 4, cg = blk & 15;
  const int t = threadIdx.x, wv = t >> 6, lane = t & 63;
  float acc[8];
#pragma unroll
  for (int j = 0; j < 8; ++j) acc[j] = 0.f;
  for (int ch = 0; ch < 4; ++ch) {
    __syncthreads();
#pragma unroll
    for (int u = t; u < 4096; u += 256) {
      const int co = u >> 7, ci = u & 127;
      wl[ci * 36 + co] = w[(cg * 32 + co) * 512 + ch * 128 + ci];
    }
    for (int u = t; u < 6272; u += 256) {
      const int ci = u / 49, s = u % 49;
      rl[ci * 64 + s] = r[b * 25088 + ch * 6272 + u];
    }
    __syncthreads();
#pragma unroll 4
    for (int ci = 0; ci < 128; ++ci) {
      const f32x4 w0 = *(const f32x4*)(wl + ci * 36 + wv * 8);
      const f32x4 w1 = *(const f32x4*)(wl + ci * 36 + wv * 8 + 4);
      const float rv = rl[ci * 64 + lane];
#pragma unroll
      for (int j = 0; j < 4; ++j) { acc[j] += w0[j] * rv; acc[4 + j] += w1[j] * rv; }
    }
  }
  if (lane < 49) {
#pragma unroll
    for (int j = 0; j < 8; ++j) {
      const int co = cg * 32 + wv * 8 + j;
      A[b * 25088 + co * 49 + lane] = acc[j] + bias[co];
    }
  }
}

// ------- bf16 MFMA GEMM, dbuf + global_load_lds(16B) + XCD chunk swizzle -------
// C[M][N] = A[M][512] * B[N][512]^T. 128x128 tile, 4 waves, 1D grid.
// MODE 0: qkv scatter (NB=12) | 1: proj +bias | 2: mlp1 relu | 3: mlp2 +resid
template <int MODE>
__global__ __launch_bounds__(256) void k_gemm(
    const unsigned short* __restrict__ A, const unsigned short* __restrict__ B,
    unsigned short* __restrict__ oq, unsigned short* __restrict__ ok,
    unsigned short* __restrict__ ov, float* __restrict__ of,
    unsigned short* __restrict__ obf, const float* __restrict__ bias,
    const float* __restrict__ resid, float* __restrict__ dout) {
  __shared__ unsigned short As[2][4096];  // [128 rows][32 k] bf16, 8KB each
  __shared__ unsigned short Bs[2][4096];
  const int t = threadIdx.x;
  constexpr int NB = (MODE == 0) ? 12 : 4;       // n-blocks per m-row
  constexpr int NWG = NB * 128;
  const int swz = ((int)blockIdx.x & 7) * (NWG >> 3) + ((int)blockIdx.x >> 3);
  const int n0 = (swz % NB) * 128, m0 = (swz / NB) * 128;
  const int w = t >> 6, lane = t & 63;
  const int wr = w >> 1, wc = w & 1, lr = lane & 15, lg = lane >> 4;
  const int row = t >> 2, q = t & 3;
  const unsigned short* gA = A + m0 * 512;
  const unsigned short* gB = B + n0 * 512;

  // stage K-tile kt into buffer cur: dest is wave-uniform base + lane*16B,
  // yielding the linear [row][32] layout (thread t -> byte t*16).
  auto stage = [&](int cur, int kt) {
    const unsigned short* sa = gA + row * 512 + kt * 32 + q * 8;
    const unsigned short* sb = gB + row * 512 + kt * 32 + q * 8;
    unsigned short* da = As[cur] + w * 512;
    unsigned short* db = Bs[cur] + w * 512;
    GLD16(sa, da);
    GLD16(sa + 32768, da + 2048);   // rows 64..127
    GLD16(sb, db);
    GLD16(sb + 32768, db + 2048);
  };

  f32x4 acc[4][4];
#pragma unroll
  for (int mi = 0; mi < 4; ++mi)
#pragma unroll
    for (int ni = 0; ni < 4; ++ni)
#pragma unroll
      for (int rr = 0; rr < 4; ++rr) acc[mi][ni][rr] = 0.f;

  stage(0, 0);
  __syncthreads();  // drains vmcnt -> buf0 ready
  int cur = 0;
  for (int kt = 0; kt < 16; ++kt) {
    if (kt < 15) stage(cur ^ 1, kt + 1);  // loads overlap this tile's compute
    const unsigned short* Ac = As[cur];
    const unsigned short* Bc = Bs[cur];
    s16x8 af[4], bfr[4];
#pragma unroll
    for (int mi = 0; mi < 4; ++mi)
      af[mi] = *(const s16x8*)(Ac + (wr * 64 + mi * 16 + lr) * 32 + lg * 8);
#pragma unroll
    for (int ni = 0; ni < 4; ++ni)
      bfr[ni] = *(const s16x8*)(Bc + (wc * 64 + ni * 16 + lr) * 32 + lg * 8);
#pragma unroll
    for (int mi = 0; mi < 4; ++mi)
#pragma unroll
      for (int ni = 0; ni < 4; ++ni)
        acc[mi][ni] = __builtin_amdgcn_mfma_f32_16x16x32_bf16(af[mi], bfr[ni],
                                                              acc[mi][ni], 0, 0, 0);
    __syncthreads();  // waves done reading cur; staged loads drained
    cur ^= 1;
  }

#pragma unroll
  for (int mi = 0; mi < 4; ++mi)
#pragma unroll
    for (int ni = 0; ni < 4; ++ni)
#pragma unroll
      for (int rr = 0; rr < 4; ++rr) {
        const int gm = m0 + wr * 64 + mi * 16 + lg * 4 + rr;
        const int gn = n0 + wc * 64 + ni * 16 + lr;
        const float val = acc[mi][ni][rr];
        if (MODE == 0) {
          const int b = gm >> 10, n = gm & 1023;
          const int hh = (gn >> 6) & 7, dd = gn & 63;
          const int idx = ((b * 8 + hh) * 1024 + n) * 64 + dd;
          const unsigned short bv = f2bf(val);
          if (gn < 512) oq[idx] = bv;
          else if (gn < 1024) ok[idx] = bv;
          else ov[idx] = bv;
        } else if (MODE == 1) {
          const float v2 = val + bias[gn];
          of[gm * 512 + gn] = v2;
          obf[gm * 512 + gn] = f2bf(v2);
        } else if (MODE == 2) {
          const float v2 = fmaxf(val + bias[gn], 0.f);
          obf[gm * 512 + gn] = f2bf(v2);
        } else {
          dout[gm * 512 + gn] = val + bias[gn] + resid[gm * 512 + gn];
        }
      }
}

// ---------------- stage 1 logits: S1[bh][ag][n] = 0.125 * A[ag].k[n] ----------------
__global__ __launch_bounds__(256) void k_attn1(const float* __restrict__ Aag,
                                               const unsigned short* __restrict__ kbf,
                                               float* __restrict__ S1) {
  __shared__ float Al[3136];
  const int blk = blockIdx.x;
  const int nt = blk & 3, h = (blk >> 2) & 7, b = blk >> 5;
  const int t = threadIdx.x;
  const float* Asrc = Aag + b * 25088 + h * 3136;
  for (int u = t; u < 3136; u += 256) Al[u] = Asrc[u];
  __syncthreads();
  const int n = nt * 256 + t;
  const unsigned short* kp = kbf + ((b * 8 + h) * 1024 + n) * 64;
  float kr[64];
#pragma unroll
  for (int i = 0; i < 8; ++i) {
    const s16x8 v = *(const s16x8*)(kp + i * 8);
#pragma unroll
    for (int j = 0; j < 8; ++j) kr[i * 8 + j] = bf2f((unsigned short)v[j]);
  }
  float* srow = S1 + (b * 8 + h) * 49 * 1024 + n;
  for (int ag = 0; ag < 49; ++ag) {
    float s0 = 0.f, s1 = 0.f, s2 = 0.f, s3 = 0.f;
#pragma unroll
    for (int dq = 0; dq < 16; ++dq) {
      const f32x4 a4 = *(const f32x4*)(Al + ag * 64 + dq * 4);  // broadcast
      s0 += a4[0] * kr[dq * 4 + 0]; s1 += a4[1] * kr[dq * 4 + 1];
      s2 += a4[2] * kr[dq * 4 + 2]; s3 += a4[3] * kr[dq * 4 + 3];
    }
    srow[ag * 1024] = (s0 + s1 + s2 + s3) * 0.125f;
  }
}

// ---------------- softmax over n (row length 1024) -> P1 bf16 ----------------
__global__ __launch_bounds__(256) void k_softmax(const float* __restrict__ S1,
                                                 unsigned short* __restrict__ P1) {
  const int row = blockIdx.x, t = threadIdx.x, w = t >> 6;
  const float* s = S1 + row * 1024;
  float v[4], m = -3.0e38f;
#pragma unroll
  for (int i = 0; i < 4; ++i) { v[i] = s[t + 256 * i]; m = fmaxf(m, v[i]); }
#pragma unroll
  for (int o = 1; o < 64; o <<= 1) m = fmaxf(m, __shfl_xor(m, o, 64));
  __shared__ float red[4];
  if ((t & 63) == 0) red[w] = m;
  __syncthreads();
  m = fmaxf(fmaxf(red[0], red[1]), fmaxf(red[2], red[3]));
  float ss = 0.f;
#pragma unroll
  for (int i = 0; i < 4; ++i) { v[i] = __expf(v[i] - m); ss += v[i]; }
  __syncthreads();
#pragma unroll
  for (int o = 1; o < 64; o <<= 1) ss += __shfl_xor(ss, o, 64);
  if ((t & 63) == 0) red[w] = ss;
  __syncthreads();
  ss = red[0] + red[1] + red[2] + red[3];
  const float inv = 1.f / ss;
  unsigned short* prow = P1 + row * 1024;
#pragma unroll
  for (int i = 0; i < 4; ++i) prow[t + 256 * i] = f2bf(v[i] * inv);
}

// ------- agg partials: aggp[ks][bh][ag][d] -------
__global__ __launch_bounds__(256) void k_agg(const unsigned short* __restrict__ P1,
                                             const unsigned short* __restrict__ vbf,
                                             float* __restrict__ aggp) {
  __shared__ float vl[128 * 64];
  __shared__ float pl[128 * 52];
  const int blk = blockIdx.x;
  const int bh = blk >> 2, ks = blk & 3;
  const int t = threadIdx.x, wv = t >> 6, lane = t & 63;
  float acc[16];
#pragma unroll
  for (int j = 0; j < 16; ++j) acc[j] = 0.f;
  const unsigned short* vbase = vbf + bh * 65536 + ks * 256 * 64;
  const unsigned short* pbase = P1 + bh * 50176 + ks * 256;
  for (int nc = 0; nc < 2; ++nc) {
    __syncthreads();
#pragma unroll
    for (int u8 = t; u8 < 1024; u8 += 256) {
      const s16x8 v = *(const s16x8*)(vbase + nc * 8192 + u8 * 8);
#pragma unroll
      for (int j = 0; j < 8; ++j) vl[u8 * 8 + j] = bf2f((unsigned short)v[j]);
    }
    for (int u = t; u < 6272; u += 256) {
      const int ag = u >> 7, n = u & 127;
      pl[n * 52 + ag] = bf2f(pbase[ag * 1024 + nc * 128 + n]);
    }
    __syncthreads();
#pragma unroll 2
    for (int n = 0; n < 128; ++n) {
      const float pv = pl[n * 52 + lane];
      const f32x4 v0 = *(const f32x4*)(vl + n * 64 + wv * 16);
      const f32x4 v1 = *(const f32x4*)(vl + n * 64 + wv * 16 + 4);
      const f32x4 v2 = *(const f32x4*)(vl + n * 64 + wv * 16 + 8);
      const f32x4 v3 = *(const f32x4*)(vl + n * 64 + wv * 16 + 12);
#pragma unroll
      for (int j = 0; j < 4; ++j) {
        acc[j] += pv * v0[j]; acc[4 + j] += pv * v1[j];
        acc[8 + j] += pv * v2[j]; acc[12 + j] += pv * v3[j];
      }
    }
  }
  __syncthreads();
  if (lane < 49) {
#pragma unroll
    for (int j = 0; j < 16; ++j) vl[lane * 68 + wv * 16 + j] = acc[j];
  }
  __syncthreads();
  float* out = aggp + (ks * 128 + bh) * 3136;
  for (int u = t; u < 3136; u += 256) out[u] = vl[(u >> 6) * 68 + (u & 63)];
}

// ------- stage 2 fused (no max pass; logits tiny): enh bf16 [B*N][C] -------
__global__ __launch_bounds__(256) void k_attn2(const float* __restrict__ Aag,
                                               const float* __restrict__ aggp,
                                               const unsigned short* __restrict__ qbf,
                                               unsigned short* __restrict__ enh) {
  __shared__ float Al[3136];
  __shared__ float Gl[3136];
  const int blk = blockIdx.x;
  const int nt = blk & 3, h = (blk >> 2) & 7, b = blk >> 5;
  const int t = threadIdx.x, bh = b * 8 + h;
  for (int u = t; u < 3136; u += 256) {
    Al[u] = Aag[b * 25088 + h * 3136 + u];
    Gl[u] = aggp[bh * 3136 + u] + aggp[(128 + bh) * 3136 + u] +
            aggp[(256 + bh) * 3136 + u] + aggp[(384 + bh) * 3136 + u];
  }
  __syncthreads();
  const int n = nt * 256 + t;
  const unsigned short* qp = qbf + (bh * 1024 + n) * 64;
  float qr[64];
#pragma unroll
  for (int i = 0; i < 8; ++i) {
    const s16x8 v = *(const s16x8*)(qp + i * 8);
#pragma unroll
    for (int j = 0; j < 8; ++j) qr[i * 8 + j] = bf2f((unsigned short)v[j]);
  }
  float accv[64];
#pragma unroll
  for (int d = 0; d < 64; ++d) accv[d] = 0.f;
  float ss = 0.f;
  for (int ag = 0; ag < 49; ++ag) {
    float s0 = 0.f, s1 = 0.f, s2 = 0.f, s3 = 0.f;
#pragma unroll
    for (int dq = 0; dq < 16; ++dq) {
      const f32x4 a4 = *(const f32x4*)(Al + ag * 64 + dq * 4);  // broadcast
      s0 += a4[0] * qr[dq * 4 + 0]; s1 += a4[1] * qr[dq * 4 + 1];
      s2 += a4[2] * qr[dq * 4 + 2]; s3 += a4[3] * qr[dq * 4 + 3];
    }
    const float p = __expf((s0 + s1 + s2 + s3) * 0.125f);
    ss += p;
#pragma unroll
    for (int dq = 0; dq < 16; ++dq) {
      const f32x4 g4 = *(const f32x4*)(Gl + ag * 64 + dq * 4);  // broadcast
#pragma unroll
      for (int j = 0; j < 4; ++j) accv[dq * 4 + j] += p * g4[j];
    }
  }
  const float inv = 1.f / ss;
  unsigned short* ep = enh + (b * 1024 + n) * 512 + h * 64;
#pragma unroll
  for (int i = 0; i < 8; ++i) {
    s16x8 pk;
#pragma unroll
    for (int j = 0; j < 8; ++j) pk[j] = (short)f2bf(accv[i * 8 + j] * inv);
    *(s16x8*)(ep + i * 8) = pk;
  }
}

extern "C" void kernel_launch(void* const* d_in, const int* in_sizes, int n_in,
                              void* d_out, int out_size, void* d_ws, size_t ws_size,
                              hipStream_t stream) {
  const float* x    = (const float*)d_in[0];
  const float* q_w  = (const float*)d_in[3];
  const float* kv_w = (const float*)d_in[4];
  const float* dw_w = (const float*)d_in[5];
  const float* dw_b = (const float*)d_in[6];
  const float* bn_g = (const float*)d_in[7];
  const float* bn_b = (const float*)d_in[8];
  const float* bn_m = (const float*)d_in[9];
  const float* bn_v = (const float*)d_in[10];
  const float* pw_w = (const float*)d_in[11];
  const float* pw_b = (const float*)d_in[12];
  const float* pj_w = (const float*)d_in[13];
  const float* pj_b = (const float*)d_in[14];
  const float* e1_w = (const float*)d_in[15];
  const float* e1_b = (const float*)d_in[16];
  const float* e2_w = (const float*)d_in[17];
  const float* e2_b = (const float*)d_in[18];

  char* base = (char*)d_ws;
  size_t off = 0;
  auto alloc = [&](size_t bytes) -> void* {
    void* r = base + off;
    off += (bytes + 255) & ~(size_t)255;
    return r;
  };
  unsigned short* Wqkv = (unsigned short*)alloc(786432ull * 2);
  unsigned short* Wpj  = (unsigned short*)alloc(262144ull * 2);
  unsigned short* W1   = (unsigned short*)alloc(262144ull * 2);
  unsigned short* W2   = (unsigned short*)alloc(262144ull * 2);
  unsigned short* xT   = (unsigned short*)alloc(8388608ull * 2);
  unsigned short* qb   = (unsigned short*)alloc(8388608ull * 2);
  unsigned short* kb   = (unsigned short*)alloc(8388608ull * 2);
  unsigned short* vb   = (unsigned short*)alloc(8388608ull * 2);
  float* pbuf = (float*)alloc(401408ull * 4);
  float* rbuf = (float*)alloc(401408ull * 4);
  float* Abuf = (float*)alloc(401408ull * 4);
  float* S1   = (float*)alloc(6422528ull * 4);
  unsigned short* P1 = (unsigned short*)alloc(6422528ull * 2);
  float* aggp = (float*)alloc(1605632ull * 4);
  unsigned short* enh  = (unsigned short*)alloc(8388608ull * 2);
  float* xout = (float*)alloc(8388608ull * 4);
  unsigned short* xoutb = (unsigned short*)alloc(8388608ull * 2);
  unsigned short* h1    = (unsigned short*)alloc(8388608ull * 2);
  (void)ws_size; (void)in_sizes; (void)n_in; (void)out_size;

  k_weights<<<1536, 256, 0, stream>>>(q_w, kv_w, pj_w, e1_w, e2_w, Wqkv, Wpj, W1, W2);
  k_transpose<<<dim3(16, 8, 16), 256, 0, stream>>>(x, xT);
  k_pool<<<8192, 64, 0, stream>>>(x, pbuf);
  k_dw<<<8192, 64, 0, stream>>>(pbuf, dw_w, dw_b, bn_g, bn_b, bn_m, bn_v, rbuf);
  k_pw<<<256, 256, 0, stream>>>(rbuf, pw_w, pw_b, Abuf);
  k_gemm<0><<<1536, 256, 0, stream>>>(xT, Wqkv, qb, kb, vb,
                                      nullptr, nullptr, nullptr, nullptr, nullptr);
  k_attn1<<<512, 256, 0, stream>>>(Abuf, kb, S1);
  k_softmax<<<6272, 256, 0, stream>>>(S1, P1);
  k_agg<<<512, 256, 0, stream>>>(P1, vb, aggp);
  k_attn2<<<512, 256, 0, stream>>>(Abuf, aggp, qb, enh);
  k_gemm<1><<<512, 256, 0, stream>>>(enh, Wpj, nullptr, nullptr, nullptr,
                                     xout, xoutb, pj_b, nullptr, nullptr);
  k_gemm<2><<<512, 256, 0, stream>>>(xoutb, W1, nullptr, nullptr, nullptr,
                                     nullptr, h1, e1_b, nullptr, nullptr);
  k_gemm<3><<<512, 256, 0, stream>>>(h1, W2, nullptr, nullptr, nullptr,
                                     nullptr, nullptr, e2_b, xout, (float*)d_out);
}

// Round 4
// 236.433 us; speedup vs baseline: 2.0666x; 1.1418x over previous
//
#include <hip/hip_runtime.h>
#include <stdint.h>

// DynamicAgentAttention — MI355X gfx950
// B=16, C=512, N=1024 (32x32), HEADS=8, hd=64, AGENT=49 (7x7 pool)

typedef float f32x4 __attribute__((ext_vector_type(4)));
typedef short s16x8 __attribute__((ext_vector_type(8)));
typedef short s16x4 __attribute__((ext_vector_type(4)));

typedef __attribute__((address_space(1))) void glob_v;
typedef __attribute__((address_space(3))) void lds_v;
#define GLD16(g, l) \
  __builtin_amdgcn_global_load_lds((glob_v*)(g), (lds_v*)(l), 16, 0, 0)

__device__ __forceinline__ float bf2f(unsigned short u) {
  union { unsigned int i; float f; } v; v.i = ((unsigned int)u) << 16; return v.f;
}
__device__ __forceinline__ unsigned short f2bf(float f) {
  union { float f; unsigned int i; } v; v.f = f;
  return (unsigned short)((v.i + 0x7FFFu + ((v.i >> 16) & 1u)) >> 16);
}

// ---------------- x [B][C][N] -> xT bf16 [B*N][C] ----------------
__global__ __launch_bounds__(256) void k_transpose(const float* __restrict__ x,
                                                   unsigned short* __restrict__ xT) {
  __shared__ float tile[64][65];
  const int b = blockIdx.z, c0 = blockIdx.y * 64, n0 = blockIdx.x * 64;
  const int t = threadIdx.x, tn = t & 63, tg = t >> 6;
#pragma unroll
  for (int i = 0; i < 16; ++i) {
    const int c_l = tg * 16 + i;
    tile[c_l][tn] = x[(b * 512 + c0 + c_l) * 1024 + n0 + tn];
  }
  __syncthreads();
#pragma unroll
  for (int i = 0; i < 16; ++i) {
    const int n_l = tg * 16 + i;
    xT[(b * 1024 + n0 + n_l) * 512 + c0 + tn] = f2bf(tile[tn][n_l]);
  }
}

// ---------------- weights fp32 -> bf16 (Wqkv = [q_w; kv_w]) ----------------
__global__ __launch_bounds__(256) void k_weights(
    const float* __restrict__ qw, const float* __restrict__ kvw,
    const float* __restrict__ pjw, const float* __restrict__ w1,
    const float* __restrict__ w2, unsigned short* __restrict__ Wqkv,
    unsigned short* __restrict__ Wpj, unsigned short* __restrict__ W1,
    unsigned short* __restrict__ W2) {
  const int u = blockIdx.x * 256 + threadIdx.x;  // float4 unit, total 393216
  const float* s; unsigned short* d; int su, du;
  if (u < 196608) { d = Wqkv; du = u;
    if (u < 65536) { s = qw; su = u; } else { s = kvw; su = u - 65536; } }
  else if (u < 262144) { s = pjw; su = u - 196608; d = Wpj; du = su; }
  else if (u < 327680) { s = w1; su = u - 262144; d = W1; du = su; }
  else { s = w2; su = u - 327680; d = W2; du = su; }
  const f32x4 val = ((const f32x4*)s)[su];
  uint2 pk;
  pk.x = (unsigned)f2bf(val[0]) | ((unsigned)f2bf(val[1]) << 16);
  pk.y = (unsigned)f2bf(val[2]) | ((unsigned)f2bf(val[3]) << 16);
  ((uint2*)d)[du] = pk;
}

// ---------------- adaptive avg pool 32x32 -> 7x7, p[b][c][49] ----------------
__global__ __launch_bounds__(64) void k_pool(const float* __restrict__ x,
                                             float* __restrict__ p) {
  __shared__ float img[1024];
  const int bc = blockIdx.x, t = threadIdx.x;
  const float* src = x + bc * 1024;
#pragma unroll
  for (int i = 0; i < 16; ++i) img[t + 64 * i] = src[t + 64 * i];
  __syncthreads();
  if (t < 49) {
    const int i = t / 7, j = t % 7;
    const int hs = (i * 32) / 7, he = ((i + 1) * 32 + 6) / 7;
    const int ws = (j * 32) / 7, we = ((j + 1) * 32 + 6) / 7;
    float s = 0.f;
    for (int ii = hs; ii < he; ++ii)
      for (int jj = ws; jj < we; ++jj) s += img[ii * 32 + jj];
    p[bc * 49 + t] = s / (float)((he - hs) * (we - ws));
  }
}

// ------- depthwise 3x3 SAME on permuted input + BN + ReLU -> r[b][c][49] -------
__global__ __launch_bounds__(64) void k_dw(
    const float* __restrict__ p, const float* __restrict__ dww,
    const float* __restrict__ dwb, const float* __restrict__ g,
    const float* __restrict__ be, const float* __restrict__ mean,
    const float* __restrict__ var, float* __restrict__ r) {
  const int bc = blockIdx.x, t = threadIdx.x;
  if (t >= 49) return;
  const int b = bc >> 9, c = bc & 511;
  const int i = t / 7, j = t % 7;
  float sum = 0.f;
#pragma unroll
  for (int ki = 0; ki < 3; ++ki)
#pragma unroll
    for (int kj = 0; kj < 3; ++kj) {
      const int ii = i + ki - 1, jj = j + kj - 1;
      if (ii < 0 || ii > 6 || jj < 0 || jj > 6) continue;
      const int f = c * 49 + ii * 7 + jj;  // permuted gather (torch reshape bug kept)
      sum += dww[c * 9 + ki * 3 + kj] * p[(b * 512 + (f & 511)) * 49 + (f >> 9)];
    }
  sum += dwb[c];
  sum = (sum - mean[c]) * rsqrtf(var[c] + 1e-5f) * g[c] + be[c];
  r[bc * 49 + t] = fmaxf(sum, 0.f);
}

// ------- pointwise 1x1 as LDS-staged GEMM: A[b][co][49] = pw_w @ r + pw_b -------
__global__ __launch_bounds__(256) void k_pw(const float* __restrict__ r,
                                            const float* __restrict__ w,
                                            const float* __restrict__ bias,
                                            float* __restrict__ A) {
  __shared__ float wl[128 * 36];
  __shared__ float rl[128 * 64];
  const int blk = blockIdx.x;
  const int b = blk >> 4, cg = blk & 15;
  const int t = threadIdx.x, wv = t >> 6, lane = t & 63;
  float acc[8];
#pragma unroll
  for (int j = 0; j < 8; ++j) acc[j] = 0.f;
  for (int ch = 0; ch < 4; ++ch) {
    __syncthreads();
#pragma unroll
    for (int u = t; u < 4096; u += 256) {
      const int co = u >> 7, ci = u & 127;
      wl[ci * 36 + co] = w[(cg * 32 + co) * 512 + ch * 128 + ci];
    }
    for (int u = t; u < 6272; u += 256) {
      const int ci = u / 49, s = u % 49;
      rl[ci * 64 + s] = r[b * 25088 + ch * 6272 + u];
    }
    __syncthreads();
#pragma unroll 4
    for (int ci = 0; ci < 128; ++ci) {
      const f32x4 w0 = *(const f32x4*)(wl + ci * 36 + wv * 8);
      const f32x4 w1 = *(const f32x4*)(wl + ci * 36 + wv * 8 + 4);
      const float rv = rl[ci * 64 + lane];
#pragma unroll
      for (int j = 0; j < 4; ++j) { acc[j] += w0[j] * rv; acc[4 + j] += w1[j] * rv; }
    }
  }
  if (lane < 49) {
#pragma unroll
    for (int j = 0; j < 8; ++j) {
      const int co = cg * 32 + wv * 8 + j;
      A[b * 25088 + co * 49 + lane] = acc[j] + bias[co];
    }
  }
}

// ------- bf16 MFMA GEMM, dbuf + global_load_lds(16B) + XCD chunk swizzle -------
// MODE 0: q/k scatter + vT pack | 1: proj +bias | 2: mlp1 relu | 3: mlp2 +resid
template <int MODE>
__global__ __launch_bounds__(256) void k_gemm(
    const unsigned short* __restrict__ A, const unsigned short* __restrict__ B,
    unsigned short* __restrict__ oq, unsigned short* __restrict__ ok,
    unsigned short* __restrict__ vt, float* __restrict__ of,
    unsigned short* __restrict__ obf, const float* __restrict__ bias,
    const float* __restrict__ resid, float* __restrict__ dout) {
  __shared__ unsigned short As[2][4096];
  __shared__ unsigned short Bs[2][4096];
  const int t = threadIdx.x;
  constexpr int NB = (MODE == 0) ? 12 : 4;
  constexpr int NWG = NB * 128;
  const int swz = ((int)blockIdx.x & 7) * (NWG >> 3) + ((int)blockIdx.x >> 3);
  const int n0 = (swz % NB) * 128, m0 = (swz / NB) * 128;
  const int w = t >> 6, lane = t & 63;
  const int wr = w >> 1, wc = w & 1, lr = lane & 15, lg = lane >> 4;
  const int row = t >> 2, q = t & 3;
  const unsigned short* gA = A + m0 * 512;
  const unsigned short* gB = B + n0 * 512;

  auto stage = [&](int cur, int kt) {
    const unsigned short* sa = gA + row * 512 + kt * 32 + q * 8;
    const unsigned short* sb = gB + row * 512 + kt * 32 + q * 8;
    unsigned short* da = As[cur] + w * 512;
    unsigned short* db = Bs[cur] + w * 512;
    GLD16(sa, da);
    GLD16(sa + 32768, da + 2048);
    GLD16(sb, db);
    GLD16(sb + 32768, db + 2048);
  };

  f32x4 acc[4][4];
#pragma unroll
  for (int mi = 0; mi < 4; ++mi)
#pragma unroll
    for (int ni = 0; ni < 4; ++ni)
#pragma unroll
      for (int rr = 0; rr < 4; ++rr) acc[mi][ni][rr] = 0.f;

  stage(0, 0);
  __syncthreads();
  int cur = 0;
  for (int kt = 0; kt < 16; ++kt) {
    if (kt < 15) stage(cur ^ 1, kt + 1);
    const unsigned short* Ac = As[cur];
    const unsigned short* Bc = Bs[cur];
    s16x8 af[4], bfr[4];
#pragma unroll
    for (int mi = 0; mi < 4; ++mi)
      af[mi] = *(const s16x8*)(Ac + (wr * 64 + mi * 16 + lr) * 32 + lg * 8);
#pragma unroll
    for (int ni = 0; ni < 4; ++ni)
      bfr[ni] = *(const s16x8*)(Bc + (wc * 64 + ni * 16 + lr) * 32 + lg * 8);
#pragma unroll
    for (int mi = 0; mi < 4; ++mi)
#pragma unroll
      for (int ni = 0; ni < 4; ++ni)
        acc[mi][ni] = __builtin_amdgcn_mfma_f32_16x16x32_bf16(af[mi], bfr[ni],
                                                              acc[mi][ni], 0, 0, 0);
    __syncthreads();
    cur ^= 1;
  }

  if (MODE == 0 && n0 >= 1024) {
    // v columns -> vt[bh][d][n] bf16, packed 4 consecutive n per store
#pragma unroll
    for (int mi = 0; mi < 4; ++mi)
#pragma unroll
      for (int ni = 0; ni < 4; ++ni) {
        const int gn = n0 + wc * 64 + ni * 16 + lr;
        const int hh = (gn >> 6) & 7, dd = gn & 63;
        const int gmb = m0 + wr * 64 + mi * 16 + lg * 4;
        const int b = gmb >> 10, nn = gmb & 1023;
        s16x4 pk;
#pragma unroll
        for (int rr = 0; rr < 4; ++rr) pk[rr] = (short)f2bf(acc[mi][ni][rr]);
        *(s16x4*)(vt + ((b * 8 + hh) * 64 + dd) * 1024 + nn) = pk;
      }
    return;
  }

#pragma unroll
  for (int mi = 0; mi < 4; ++mi)
#pragma unroll
    for (int ni = 0; ni < 4; ++ni)
#pragma unroll
      for (int rr = 0; rr < 4; ++rr) {
        const int gm = m0 + wr * 64 + mi * 16 + lg * 4 + rr;
        const int gn = n0 + wc * 64 + ni * 16 + lr;
        const float val = acc[mi][ni][rr];
        if (MODE == 0) {
          const int b = gm >> 10, n = gm & 1023;
          const int hh = (gn >> 6) & 7, dd = gn & 63;
          const int idx = ((b * 8 + hh) * 1024 + n) * 64 + dd;
          const unsigned short bv = f2bf(val);
          if (gn < 512) oq[idx] = bv;
          else ok[idx] = bv;
        } else if (MODE == 1) {
          const float v2 = val + bias[gn];
          of[gm * 512 + gn] = v2;
          obf[gm * 512 + gn] = f2bf(v2);
        } else if (MODE == 2) {
          const float v2 = fmaxf(val + bias[gn], 0.f);
          obf[gm * 512 + gn] = f2bf(v2);
        } else {
          dout[gm * 512 + gn] = val + bias[gn] + resid[gm * 512 + gn];
        }
      }
}

// ------- stage-1 agent flash: numT[half][bh][d][ag], den[half][bh][ag] -------
// grid 256 = bh*2 + half(512 n). 4 waves; wave w owns ag-strip [w*16, w*16+16).
// All LDS tiles rows padded to 72 shorts (144B = 9*16B -> conflict-free quads).
__global__ __launch_bounds__(256) void k_aflash(
    const float* __restrict__ Abuf, const unsigned short* __restrict__ kbf,
    const unsigned short* __restrict__ vt, float* __restrict__ numT,
    float* __restrict__ denG) {
  __shared__ unsigned short A_lds[64 * 72];   // [ag][d]
  __shared__ unsigned short K_lds[64 * 72];   // [n][d] per chunk
  __shared__ unsigned short VT_lds[64 * 72];  // [d][n] per chunk
  __shared__ unsigned short P_lds[64 * 72];   // [ag][n], wave strips
  const int blk = blockIdx.x;
  const int bh = blk >> 1, half = blk & 1;
  const int b = bh >> 3, h = bh & 7;
  const int t = threadIdx.x, w = t >> 6, lane = t & 63;
  const int lr = lane & 15, lg = lane >> 4;

  for (int u = t; u < 64 * 72; u += 256) A_lds[u] = 0;
  __syncthreads();
  for (int u = t; u < 3136; u += 256) {
    const int d = u / 49, ag = u % 49;
    A_lds[ag * 72 + d] = f2bf(Abuf[b * 25088 + (h * 64 + d) * 49 + ag]);
  }

  const unsigned short* kbase = kbf + bh * 65536 + half * 512 * 64;
  const unsigned short* vbase = vt + bh * 65536 + half * 512;

  f32x4 num[4];
#pragma unroll
  for (int ni = 0; ni < 4; ++ni)
#pragma unroll
    for (int rr = 0; rr < 4; ++rr) num[ni][rr] = 0.f;
  float den[4] = {0.f, 0.f, 0.f, 0.f};

  for (int c = 0; c < 8; ++c) {
    const int n0 = c * 64;
    __syncthreads();  // prev chunk reads done (c=0: A_lds writes done)
    for (int u = t; u < 512; u += 256) {
      const int rw = u >> 3, qq = u & 7;
      *(s16x8*)(K_lds + rw * 72 + qq * 8) =
          *(const s16x8*)(kbase + (n0 + rw) * 64 + qq * 8);
      *(s16x8*)(VT_lds + rw * 72 + qq * 8) =
          *(const s16x8*)(vbase + rw * 1024 + n0 + qq * 8);
    }
    __syncthreads();
    // QK: S-strip [16 ag][64 n], C: row ag = w*16+lg*4+rr, col n = ni*16+lr
    f32x4 s[4];
#pragma unroll
    for (int ni = 0; ni < 4; ++ni)
#pragma unroll
      for (int rr = 0; rr < 4; ++rr) s[ni][rr] = 0.f;
#pragma unroll
    for (int kk = 0; kk < 2; ++kk) {
      const s16x8 afr = *(const s16x8*)(A_lds + (w * 16 + lr) * 72 + kk * 32 + lg * 8);
#pragma unroll
      for (int ni = 0; ni < 4; ++ni) {
        const s16x8 bfr =
            *(const s16x8*)(K_lds + (ni * 16 + lr) * 72 + kk * 32 + lg * 8);
        s[ni] = __builtin_amdgcn_mfma_f32_16x16x32_bf16(afr, bfr, s[ni], 0, 0, 0);
      }
    }
    // exp (no max; logits tiny), den partials, P -> LDS [ag][n]
#pragma unroll
    for (int ni = 0; ni < 4; ++ni)
#pragma unroll
      for (int rr = 0; rr < 4; ++rr) {
        const float p = __expf(s[ni][rr] * 0.125f);
        den[rr] += p;
        P_lds[(w * 16 + lg * 4 + rr) * 72 + ni * 16 + lr] = f2bf(p);
      }
    // PV: num[ag-strip][d] += P[ag][n] * VT[d][n]
#pragma unroll
    for (int kk = 0; kk < 2; ++kk) {
      const s16x8 pa = *(const s16x8*)(P_lds + (w * 16 + lr) * 72 + kk * 32 + lg * 8);
#pragma unroll
      for (int ni = 0; ni < 4; ++ni) {
        const s16x8 vfr =
            *(const s16x8*)(VT_lds + (ni * 16 + lr) * 72 + kk * 32 + lg * 8);
        num[ni] = __builtin_amdgcn_mfma_f32_16x16x32_bf16(pa, vfr, num[ni], 0, 0, 0);
      }
    }
  }
  // den: reduce over lr lanes (cols) -> den for ag = w*16+lg*4+rr
#pragma unroll
  for (int rr = 0; rr < 4; ++rr) {
#pragma unroll
    for (int o = 1; o < 16; o <<= 1) den[rr] += __shfl_xor(den[rr], o, 64);
  }
  const int obase = (half * 128 + bh) * 4096;
#pragma unroll
  for (int ni = 0; ni < 4; ++ni)
    *(f32x4*)(numT + obase + (ni * 16 + lr) * 64 + w * 16 + lg * 4) = num[ni];
  if (lr == 0) {
    f32x4 dv;
#pragma unroll
    for (int rr = 0; rr < 4; ++rr) dv[rr] = den[rr];
    *(f32x4*)(denG + (half * 128 + bh) * 64 + w * 16 + lg * 4) = dv;
  }
}

// ------- stage-2 MFMA: enh[n][C] = softmax49(q.A^T) @ agg -------
// grid 512 = bh*4 + nq(256 n). 4 waves x 64 n-rows each.
__global__ __launch_bounds__(256) void k_attn2(
    const float* __restrict__ Abuf, const float* __restrict__ numT,
    const float* __restrict__ denG, const unsigned short* __restrict__ qbf,
    unsigned short* __restrict__ enh) {
  __shared__ unsigned short A_lds[64 * 72];       // [ag][d]
  __shared__ unsigned short G_lds[64 * 72];       // aggT [d][ag]
  __shared__ unsigned short P2_lds[4][64 * 72];   // per-wave [n][ag]
  __shared__ float den_lds[64];
  const int blk = blockIdx.x;
  const int bh = blk >> 2, nq = blk & 3;
  const int b = bh >> 3, h = bh & 7;
  const int t = threadIdx.x, w = t >> 6, lane = t & 63;
  const int lr = lane & 15, lg = lane >> 4;

  if (t < 64) den_lds[t] = 1.f / (denG[bh * 64 + t] + denG[8192 + bh * 64 + t]);
  for (int u = t; u < 64 * 72; u += 256) A_lds[u] = 0;
  __syncthreads();
  for (int u = t; u < 3136; u += 256) {
    const int d = u / 49, ag = u % 49;
    A_lds[ag * 72 + d] = f2bf(Abuf[b * 25088 + (h * 64 + d) * 49 + ag]);
  }
  for (int u = t; u < 4096; u += 256) {
    const int d = u >> 6, ag = u & 63;
    const float v = (numT[bh * 4096 + u] + numT[524288 + bh * 4096 + u]) * den_lds[ag];
    G_lds[d * 72 + ag] = f2bf(v);
  }
  __syncthreads();

  const int nbase = nq * 256 + w * 64;
  const unsigned short* qp = qbf + (bh * 1024 + nbase) * 64;
  // q A-op frags: lane: n-row = mi*16+lr, k-d = kk*32+lg*8
  s16x8 qf[4][2];
#pragma unroll
  for (int mi = 0; mi < 4; ++mi)
#pragma unroll
    for (int kk = 0; kk < 2; ++kk)
      qf[mi][kk] = *(const s16x8*)(qp + (mi * 16 + lr) * 64 + kk * 32 + lg * 8);

  // L[n][ag]
  f32x4 L[4][4];
#pragma unroll
  for (int mi = 0; mi < 4; ++mi)
#pragma unroll
    for (int ni = 0; ni < 4; ++ni)
#pragma unroll
      for (int rr = 0; rr < 4; ++rr) L[mi][ni][rr] = 0.f;
#pragma unroll
  for (int kk = 0; kk < 2; ++kk)
#pragma unroll
    for (int ni = 0; ni < 4; ++ni) {
      const s16x8 bfr = *(const s16x8*)(A_lds + (ni * 16 + lr) * 72 + kk * 32 + lg * 8);
#pragma unroll
      for (int mi = 0; mi < 4; ++mi)
        L[mi][ni] = __builtin_amdgcn_mfma_f32_16x16x32_bf16(qf[mi][kk], bfr,
                                                            L[mi][ni], 0, 0, 0);
    }
  // softmax over ag (cols): mask pads, exp, 16-lane row reduce
  unsigned short* pw = P2_lds[w];
#pragma unroll
  for (int mi = 0; mi < 4; ++mi) {
    float ps[4][4];
    float rs[4];
#pragma unroll
    for (int rr = 0; rr < 4; ++rr) rs[rr] = 0.f;
#pragma unroll
    for (int ni = 0; ni < 4; ++ni) {
      const bool valid = (ni < 3) | (lr == 0);
#pragma unroll
      for (int rr = 0; rr < 4; ++rr) {
        const float p = valid ? __expf(L[mi][ni][rr] * 0.125f) : 0.f;
        ps[ni][rr] = p;
        rs[rr] += p;
      }
    }
#pragma unroll
    for (int rr = 0; rr < 4; ++rr) {
#pragma unroll
      for (int o = 1; o < 16; o <<= 1) rs[rr] += __shfl_xor(rs[rr], o, 64);
      rs[rr] = 1.f / rs[rr];
    }
#pragma unroll
    for (int ni = 0; ni < 4; ++ni)
#pragma unroll
      for (int rr = 0; rr < 4; ++rr)
        pw[(mi * 16 + lg * 4 + rr) * 72 + ni * 16 + lr] = f2bf(ps[ni][rr] * rs[rr]);
  }
  // PV2: enh[n][d] = P2[n][ag] * aggT[d][ag]
#pragma unroll
  for (int mi = 0; mi < 4; ++mi) {
    f32x4 e[4];
#pragma unroll
    for (int ni = 0; ni < 4; ++ni)
#pragma unroll
      for (int rr = 0; rr < 4; ++rr) e[ni][rr] = 0.f;
#pragma unroll
    for (int kk = 0; kk < 2; ++kk) {
      const s16x8 pa = *(const s16x8*)(pw + (mi * 16 + lr) * 72 + kk * 32 + lg * 8);
#pragma unroll
      for (int ni = 0; ni < 4; ++ni) {
        const s16x8 gb = *(const s16x8*)(G_lds + (ni * 16 + lr) * 72 + kk * 32 + lg * 8);
        e[ni] = __builtin_amdgcn_mfma_f32_16x16x32_bf16(pa, gb, e[ni], 0, 0, 0);
      }
    }
#pragma unroll
    for (int ni = 0; ni < 4; ++ni)
#pragma unroll
      for (int rr = 0; rr < 4; ++rr) {
        const int n = nbase + mi * 16 + lg * 4 + rr;
        enh[(b * 1024 + n) * 512 + h * 64 + ni * 16 + lr] = f2bf(e[ni][rr]);
      }
  }
}

extern "C" void kernel_launch(void* const* d_in, const int* in_sizes, int n_in,
                              void* d_out, int out_size, void* d_ws, size_t ws_size,
                              hipStream_t stream) {
  const float* x    = (const float*)d_in[0];
  const float* q_w  = (const float*)d_in[3];
  const float* kv_w = (const float*)d_in[4];
  const float* dw_w = (const float*)d_in[5];
  const float* dw_b = (const float*)d_in[6];
  const float* bn_g = (const float*)d_in[7];
  const float* bn_b = (const float*)d_in[8];
  const float* bn_m = (const float*)d_in[9];
  const float* bn_v = (const float*)d_in[10];
  const float* pw_w = (const float*)d_in[11];
  const float* pw_b = (const float*)d_in[12];
  const float* pj_w = (const float*)d_in[13];
  const float* pj_b = (const float*)d_in[14];
  const float* e1_w = (const float*)d_in[15];
  const float* e1_b = (const float*)d_in[16];
  const float* e2_w = (const float*)d_in[17];
  const float* e2_b = (const float*)d_in[18];

  char* base = (char*)d_ws;
  size_t off = 0;
  auto alloc = [&](size_t bytes) -> void* {
    void* r = base + off;
    off += (bytes + 255) & ~(size_t)255;
    return r;
  };
  unsigned short* Wqkv = (unsigned short*)alloc(786432ull * 2);
  unsigned short* Wpj  = (unsigned short*)alloc(262144ull * 2);
  unsigned short* W1   = (unsigned short*)alloc(262144ull * 2);
  unsigned short* W2   = (unsigned short*)alloc(262144ull * 2);
  unsigned short* xT   = (unsigned short*)alloc(8388608ull * 2);
  unsigned short* qb   = (unsigned short*)alloc(8388608ull * 2);
  unsigned short* kb   = (unsigned short*)alloc(8388608ull * 2);
  unsigned short* vt   = (unsigned short*)alloc(8388608ull * 2);
  float* pbuf = (float*)alloc(401408ull * 4);
  float* rbuf = (float*)alloc(401408ull * 4);
  float* Abuf = (float*)alloc(401408ull * 4);
  float* numT = (float*)alloc(1048576ull * 4);
  float* denG = (float*)alloc(16384ull * 4);
  unsigned short* enh  = (unsigned short*)alloc(8388608ull * 2);
  float* xout = (float*)alloc(8388608ull * 4);
  unsigned short* xoutb = (unsigned short*)alloc(8388608ull * 2);
  unsigned short* h1    = (unsigned short*)alloc(8388608ull * 2);
  (void)ws_size; (void)in_sizes; (void)n_in; (void)out_size;

  k_weights<<<1536, 256, 0, stream>>>(q_w, kv_w, pj_w, e1_w, e2_w, Wqkv, Wpj, W1, W2);
  k_transpose<<<dim3(16, 8, 16), 256, 0, stream>>>(x, xT);
  k_pool<<<8192, 64, 0, stream>>>(x, pbuf);
  k_dw<<<8192, 64, 0, stream>>>(pbuf, dw_w, dw_b, bn_g, bn_b, bn_m, bn_v, rbuf);
  k_pw<<<256, 256, 0, stream>>>(rbuf, pw_w, pw_b, Abuf);
  k_gemm<0><<<1536, 256, 0, stream>>>(xT, Wqkv, qb, kb, vt,
                                      nullptr, nullptr, nullptr, nullptr, nullptr);
  k_aflash<<<256, 256, 0, stream>>>(Abuf, kb, vt, numT, denG);
  k_attn2<<<512, 256, 0, stream>>>(Abuf, numT, denG, qb, enh);
  k_gemm<1><<<512, 256, 0, stream>>>(enh, Wpj, nullptr, nullptr, nullptr,
                                     xout, xoutb, pj_b, nullptr, nullptr);
  k_gemm<2><<<512, 256, 0, stream>>>(xoutb, W1, nullptr, nullptr, nullptr,
                                     nullptr, h1, e1_b, nullptr, nullptr);
  k_gemm<3><<<512, 256, 0, stream>>>(h1, W2, nullptr, nullptr, nullptr,
                                     nullptr, nullptr, e2_b, xout, (float*)d_out);
}

// Round 5
// 210.045 us; speedup vs baseline: 2.3263x; 1.1256x over previous
//
#include <hip/hip_runtime.h>
#include <stdint.h>

// DynamicAgentAttention — MI355X gfx950
// B=16, C=512, N=1024 (32x32), HEADS=8, hd=64, AGENT=49 (7x7 pool)

typedef float f32x4 __attribute__((ext_vector_type(4)));
typedef short s16x8 __attribute__((ext_vector_type(8)));

typedef __attribute__((address_space(1))) void glob_v;
typedef __attribute__((address_space(3))) void lds_v;
#define GLD16(g, l) \
  __builtin_amdgcn_global_load_lds((glob_v*)(g), (lds_v*)(l), 16, 0, 0)

__device__ __forceinline__ float bf2f(unsigned short u) {
  union { unsigned int i; float f; } v; v.i = ((unsigned int)u) << 16; return v.f;
}
__device__ __forceinline__ unsigned short f2bf(float f) {
  union { float f; unsigned int i; } v; v.f = f;
  return (unsigned short)((v.i + 0x7FFFu + ((v.i >> 16) & 1u)) >> 16);
}

// ---------------- x [B][C][N] -> xT bf16 [B*N][C] ----------------
__global__ __launch_bounds__(256) void k_transpose(const float* __restrict__ x,
                                                   unsigned short* __restrict__ xT) {
  __shared__ float tile[64][65];
  const int b = blockIdx.z, c0 = blockIdx.y * 64, n0 = blockIdx.x * 64;
  const int t = threadIdx.x, tn = t & 63, tg = t >> 6;
#pragma unroll
  for (int i = 0; i < 16; ++i) {
    const int c_l = tg * 16 + i;
    tile[c_l][tn] = x[(b * 512 + c0 + c_l) * 1024 + n0 + tn];
  }
  __syncthreads();
#pragma unroll
  for (int i = 0; i < 16; ++i) {
    const int n_l = tg * 16 + i;
    xT[(b * 1024 + n0 + n_l) * 512 + c0 + tn] = f2bf(tile[tn][n_l]);
  }
}

// ---------------- weights fp32 -> bf16 (Wqkv = [q_w; kv_w]) ----------------
__global__ __launch_bounds__(256) void k_weights(
    const float* __restrict__ qw, const float* __restrict__ kvw,
    const float* __restrict__ pjw, const float* __restrict__ w1,
    const float* __restrict__ w2, unsigned short* __restrict__ Wqkv,
    unsigned short* __restrict__ Wpj, unsigned short* __restrict__ W1,
    unsigned short* __restrict__ W2) {
  const int u = blockIdx.x * 256 + threadIdx.x;  // float4 unit, total 393216
  const float* s; unsigned short* d; int su, du;
  if (u < 196608) { d = Wqkv; du = u;
    if (u < 65536) { s = qw; su = u; } else { s = kvw; su = u - 65536; } }
  else if (u < 262144) { s = pjw; su = u - 196608; d = Wpj; du = su; }
  else if (u < 327680) { s = w1; su = u - 262144; d = W1; du = su; }
  else { s = w2; su = u - 327680; d = W2; du = su; }
  const f32x4 val = ((const f32x4*)s)[su];
  uint2 pk;
  pk.x = (unsigned)f2bf(val[0]) | ((unsigned)f2bf(val[1]) << 16);
  pk.y = (unsigned)f2bf(val[2]) | ((unsigned)f2bf(val[3]) << 16);
  ((uint2*)d)[du] = pk;
}

// ---------------- adaptive avg pool 32x32 -> 7x7, p[b][c][49] ----------------
__global__ __launch_bounds__(64) void k_pool(const float* __restrict__ x,
                                             float* __restrict__ p) {
  __shared__ float img[1024];
  const int bc = blockIdx.x, t = threadIdx.x;
  const float* src = x + bc * 1024;
#pragma unroll
  for (int i = 0; i < 16; ++i) img[t + 64 * i] = src[t + 64 * i];
  __syncthreads();
  if (t < 49) {
    const int i = t / 7, j = t % 7;
    const int hs = (i * 32) / 7, he = ((i + 1) * 32 + 6) / 7;
    const int ws = (j * 32) / 7, we = ((j + 1) * 32 + 6) / 7;
    float s = 0.f;
    for (int ii = hs; ii < he; ++ii)
      for (int jj = ws; jj < we; ++jj) s += img[ii * 32 + jj];
    p[bc * 49 + t] = s / (float)((he - hs) * (we - ws));
  }
}

// ------- depthwise 3x3 SAME on permuted input + BN + ReLU -> r[b][c][49] -------
__global__ __launch_bounds__(64) void k_dw(
    const float* __restrict__ p, const float* __restrict__ dww,
    const float* __restrict__ dwb, const float* __restrict__ g,
    const float* __restrict__ be, const float* __restrict__ mean,
    const float* __restrict__ var, float* __restrict__ r) {
  const int bc = blockIdx.x, t = threadIdx.x;
  if (t >= 49) return;
  const int b = bc >> 9, c = bc & 511;
  const int i = t / 7, j = t % 7;
  float sum = 0.f;
#pragma unroll
  for (int ki = 0; ki < 3; ++ki)
#pragma unroll
    for (int kj = 0; kj < 3; ++kj) {
      const int ii = i + ki - 1, jj = j + kj - 1;
      if (ii < 0 || ii > 6 || jj < 0 || jj > 6) continue;
      const int f = c * 49 + ii * 7 + jj;  // permuted gather (torch reshape bug kept)
      sum += dww[c * 9 + ki * 3 + kj] * p[(b * 512 + (f & 511)) * 49 + (f >> 9)];
    }
  sum += dwb[c];
  sum = (sum - mean[c]) * rsqrtf(var[c] + 1e-5f) * g[c] + be[c];
  r[bc * 49 + t] = fmaxf(sum, 0.f);
}

// ------- pointwise 1x1 as LDS-staged GEMM: A[b][co][49] = pw_w @ r + pw_b -------
__global__ __launch_bounds__(256) void k_pw(const float* __restrict__ r,
                                            const float* __restrict__ w,
                                            const float* __restrict__ bias,
                                            float* __restrict__ A) {
  __shared__ float wl[128 * 36];
  __shared__ float rl[128 * 64];
  const int blk = blockIdx.x;
  const int b = blk >> 4, cg = blk & 15;
  const int t = threadIdx.x, wv = t >> 6, lane = t & 63;
  float acc[8];
#pragma unroll
  for (int j = 0; j < 8; ++j) acc[j] = 0.f;
  for (int ch = 0; ch < 4; ++ch) {
    __syncthreads();
#pragma unroll
    for (int u = t; u < 4096; u += 256) {
      const int co = u >> 7, ci = u & 127;
      wl[ci * 36 + co] = w[(cg * 32 + co) * 512 + ch * 128 + ci];
    }
    for (int u = t; u < 6272; u += 256) {
      const int ci = u / 49, s = u % 49;
      rl[ci * 64 + s] = r[b * 25088 + ch * 6272 + u];
    }
    __syncthreads();
#pragma unroll 4
    for (int ci = 0; ci < 128; ++ci) {
      const f32x4 w0 = *(const f32x4*)(wl + ci * 36 + wv * 8);
      const f32x4 w1 = *(const f32x4*)(wl + ci * 36 + wv * 8 + 4);
      const float rv = rl[ci * 64 + lane];
#pragma unroll
      for (int j = 0; j < 4; ++j) { acc[j] += w0[j] * rv; acc[4 + j] += w1[j] * rv; }
    }
  }
  if (lane < 49) {
#pragma unroll
    for (int j = 0; j < 8; ++j) {
      const int co = cg * 32 + wv * 8 + j;
      A[b * 25088 + co * 49 + lane] = acc[j] + bias[co];
    }
  }
}

// ------- bf16 MFMA GEMM, dbuf + global_load_lds(16B) + XCD chunk swizzle -------
// MODE 0: qkv scatter | 1: proj +bias | 2: mlp1 relu | 3: mlp2 +resid
template <int MODE>
__global__ __launch_bounds__(256) void k_gemm(
    const unsigned short* __restrict__ A, const unsigned short* __restrict__ B,
    unsigned short* __restrict__ oq, unsigned short* __restrict__ ok,
    unsigned short* __restrict__ ov, float* __restrict__ of,
    unsigned short* __restrict__ obf, const float* __restrict__ bias,
    const float* __restrict__ resid, float* __restrict__ dout) {
  __shared__ unsigned short As[2][4096];
  __shared__ unsigned short Bs[2][4096];
  const int t = threadIdx.x;
  constexpr int NB = (MODE == 0) ? 12 : 4;
  constexpr int NWG = NB * 128;
  const int swz = ((int)blockIdx.x & 7) * (NWG >> 3) + ((int)blockIdx.x >> 3);
  const int n0 = (swz % NB) * 128, m0 = (swz / NB) * 128;
  const int w = t >> 6, lane = t & 63;
  const int wr = w >> 1, wc = w & 1, lr = lane & 15, lg = lane >> 4;
  const int row = t >> 2, q = t & 3;
  const unsigned short* gA = A + m0 * 512;
  const unsigned short* gB = B + n0 * 512;

  auto stage = [&](int cur, int kt) {
    const unsigned short* sa = gA + row * 512 + kt * 32 + q * 8;
    const unsigned short* sb = gB + row * 512 + kt * 32 + q * 8;
    unsigned short* da = As[cur] + w * 512;
    unsigned short* db = Bs[cur] + w * 512;
    GLD16(sa, da);
    GLD16(sa + 32768, da + 2048);
    GLD16(sb, db);
    GLD16(sb + 32768, db + 2048);
  };

  f32x4 acc[4][4];
#pragma unroll
  for (int mi = 0; mi < 4; ++mi)
#pragma unroll
    for (int ni = 0; ni < 4; ++ni)
#pragma unroll
      for (int rr = 0; rr < 4; ++rr) acc[mi][ni][rr] = 0.f;

  stage(0, 0);
  __syncthreads();
  int cur = 0;
  for (int kt = 0; kt < 16; ++kt) {
    if (kt < 15) stage(cur ^ 1, kt + 1);
    const unsigned short* Ac = As[cur];
    const unsigned short* Bc = Bs[cur];
    s16x8 af[4], bfr[4];
#pragma unroll
    for (int mi = 0; mi < 4; ++mi)
      af[mi] = *(const s16x8*)(Ac + (wr * 64 + mi * 16 + lr) * 32 + lg * 8);
#pragma unroll
    for (int ni = 0; ni < 4; ++ni)
      bfr[ni] = *(const s16x8*)(Bc + (wc * 64 + ni * 16 + lr) * 32 + lg * 8);
#pragma unroll
    for (int mi = 0; mi < 4; ++mi)
#pragma unroll
      for (int ni = 0; ni < 4; ++ni)
        acc[mi][ni] = __builtin_amdgcn_mfma_f32_16x16x32_bf16(af[mi], bfr[ni],
                                                              acc[mi][ni], 0, 0, 0);
    __syncthreads();
    cur ^= 1;
  }

#pragma unroll
  for (int mi = 0; mi < 4; ++mi)
#pragma unroll
    for (int ni = 0; ni < 4; ++ni)
#pragma unroll
      for (int rr = 0; rr < 4; ++rr) {
        const int gm = m0 + wr * 64 + mi * 16 + lg * 4 + rr;
        const int gn = n0 + wc * 64 + ni * 16 + lr;
        const float val = acc[mi][ni][rr];
        if (MODE == 0) {
          const int b = gm >> 10, n = gm & 1023;
          const int hh = (gn >> 6) & 7, dd = gn & 63;
          const int idx = ((b * 8 + hh) * 1024 + n) * 64 + dd;
          const unsigned short bv = f2bf(val);
          if (gn < 512) oq[idx] = bv;
          else if (gn < 1024) ok[idx] = bv;
          else ov[idx] = bv;
        } else if (MODE == 1) {
          const float v2 = val + bias[gn];
          of[gm * 512 + gn] = v2;
          obf[gm * 512 + gn] = f2bf(v2);
        } else if (MODE == 2) {
          const float v2 = fmaxf(val + bias[gn], 0.f);
          obf[gm * 512 + gn] = f2bf(v2);
        } else {
          dout[gm * 512 + gn] = val + bias[gn] + resid[gm * 512 + gn];
        }
      }
}

// ------- stage-1 agent flash: numT[half][bh][d][ag], den[half][bh][ag] -------
// grid 256 = bh*2 + half(512 n). 4 waves; wave w owns ag-strip [w*16, w*16+16).
// VT_lds built by transpose-on-stage from v [bh][n][d] (coalesced global reads,
// 2-way-free scalar LDS column writes). Rows padded to 72 shorts.
__global__ __launch_bounds__(256) void k_aflash(
    const float* __restrict__ Abuf, const unsigned short* __restrict__ kbf,
    const unsigned short* __restrict__ vbf, float* __restrict__ numT,
    float* __restrict__ denG) {
  __shared__ unsigned short A_lds[64 * 72];   // [ag][d]
  __shared__ unsigned short K_lds[64 * 72];   // [n][d] per chunk
  __shared__ unsigned short VT_lds[64 * 72];  // [d][n] per chunk (transposed stage)
  __shared__ unsigned short P_lds[64 * 72];   // [ag][n], wave strips
  const int blk = blockIdx.x;
  const int bh = blk >> 1, half = blk & 1;
  const int b = bh >> 3, h = bh & 7;
  const int t = threadIdx.x, w = t >> 6, lane = t & 63;
  const int lr = lane & 15, lg = lane >> 4;

  for (int u = t; u < 64 * 72; u += 256) A_lds[u] = 0;
  __syncthreads();
  for (int u = t; u < 3136; u += 256) {
    const int d = u / 49, ag = u % 49;
    A_lds[ag * 72 + d] = f2bf(Abuf[b * 25088 + (h * 64 + d) * 49 + ag]);
  }

  const unsigned short* kbase = kbf + bh * 65536 + half * 512 * 64;
  const unsigned short* vbase = vbf + bh * 65536 + half * 512 * 64;

  f32x4 num[4];
#pragma unroll
  for (int ni = 0; ni < 4; ++ni)
#pragma unroll
    for (int rr = 0; rr < 4; ++rr) num[ni][rr] = 0.f;
  float den[4] = {0.f, 0.f, 0.f, 0.f};

  for (int c = 0; c < 8; ++c) {
    const int n0 = c * 64;
    __syncthreads();  // prev chunk reads done (c=0: A_lds writes done)
    // K rows, straight copy
#pragma unroll
    for (int u = t; u < 512; u += 256) {
      const int rw = u >> 3, qq = u & 7;
      *(s16x8*)(K_lds + rw * 72 + qq * 8) =
          *(const s16x8*)(kbase + (n0 + rw) * 64 + qq * 8);
    }
    // V rows -> VT_lds[d][n]: coalesced-ish reads (L1 absorbs), scalar col writes
#pragma unroll
    for (int u = t; u < 512; u += 256) {
      const int n_l = u & 63, qq = u >> 6;  // qq 0..3 then 4..7
      const s16x8 v = *(const s16x8*)(vbase + (n0 + n_l) * 64 + qq * 8);
#pragma unroll
      for (int j = 0; j < 8; ++j)
        VT_lds[(qq * 8 + j) * 72 + n_l] = (unsigned short)v[j];
    }
    __syncthreads();
    // QK: S-strip [16 ag][64 n]
    f32x4 s[4];
#pragma unroll
    for (int ni = 0; ni < 4; ++ni)
#pragma unroll
      for (int rr = 0; rr < 4; ++rr) s[ni][rr] = 0.f;
#pragma unroll
    for (int kk = 0; kk < 2; ++kk) {
      const s16x8 afr = *(const s16x8*)(A_lds + (w * 16 + lr) * 72 + kk * 32 + lg * 8);
#pragma unroll
      for (int ni = 0; ni < 4; ++ni) {
        const s16x8 bfr =
            *(const s16x8*)(K_lds + (ni * 16 + lr) * 72 + kk * 32 + lg * 8);
        s[ni] = __builtin_amdgcn_mfma_f32_16x16x32_bf16(afr, bfr, s[ni], 0, 0, 0);
      }
    }
    // exp (no max; logits tiny), den partials, P -> LDS [ag][n]
#pragma unroll
    for (int ni = 0; ni < 4; ++ni)
#pragma unroll
      for (int rr = 0; rr < 4; ++rr) {
        const float p = __expf(s[ni][rr] * 0.125f);
        den[rr] += p;
        P_lds[(w * 16 + lg * 4 + rr) * 72 + ni * 16 + lr] = f2bf(p);
      }
    // PV: num[ag-strip][d] += P[ag][n] * VT[d][n]
#pragma unroll
    for (int kk = 0; kk < 2; ++kk) {
      const s16x8 pa = *(const s16x8*)(P_lds + (w * 16 + lr) * 72 + kk * 32 + lg * 8);
#pragma unroll
      for (int ni = 0; ni < 4; ++ni) {
        const s16x8 vfr =
            *(const s16x8*)(VT_lds + (ni * 16 + lr) * 72 + kk * 32 + lg * 8);
        num[ni] = __builtin_amdgcn_mfma_f32_16x16x32_bf16(pa, vfr, num[ni], 0, 0, 0);
      }
    }
  }
  // den: reduce over lr lanes (cols) -> den for ag = w*16+lg*4+rr
#pragma unroll
  for (int rr = 0; rr < 4; ++rr) {
#pragma unroll
    for (int o = 1; o < 16; o <<= 1) den[rr] += __shfl_xor(den[rr], o, 64);
  }
  const int obase = (half * 128 + bh) * 4096;
#pragma unroll
  for (int ni = 0; ni < 4; ++ni)
    *(f32x4*)(numT + obase + (ni * 16 + lr) * 64 + w * 16 + lg * 4) = num[ni];
  if (lr == 0) {
    f32x4 dv;
#pragma unroll
    for (int rr = 0; rr < 4; ++rr) dv[rr] = den[rr];
    *(f32x4*)(denG + (half * 128 + bh) * 64 + w * 16 + lg * 4) = dv;
  }
}

// ------- stage-2 MFMA: enh[n][C] = softmax49(q.A^T) @ agg -------
// grid 512 = bh*4 + nq(256 n). 4 waves x 64 n-rows each.
__global__ __launch_bounds__(256) void k_attn2(
    const float* __restrict__ Abuf, const float* __restrict__ numT,
    const float* __restrict__ denG, const unsigned short* __restrict__ qbf,
    unsigned short* __restrict__ enh) {
  __shared__ unsigned short A_lds[64 * 72];       // [ag][d]
  __shared__ unsigned short G_lds[64 * 72];       // aggT [d][ag]
  __shared__ unsigned short P2_lds[4][64 * 72];   // per-wave [n][ag]
  __shared__ float den_lds[64];
  const int blk = blockIdx.x;
  const int bh = blk >> 2, nq = blk & 3;
  const int b = bh >> 3, h = bh & 7;
  const int t = threadIdx.x, w = t >> 6, lane = t & 63;
  const int lr = lane & 15, lg = lane >> 4;

  if (t < 64) den_lds[t] = 1.f / (denG[bh * 64 + t] + denG[8192 + bh * 64 + t]);
  for (int u = t; u < 64 * 72; u += 256) A_lds[u] = 0;
  __syncthreads();
  for (int u = t; u < 3136; u += 256) {
    const int d = u / 49, ag = u % 49;
    A_lds[ag * 72 + d] = f2bf(Abuf[b * 25088 + (h * 64 + d) * 49 + ag]);
  }
  for (int u = t; u < 4096; u += 256) {
    const int d = u >> 6, ag = u & 63;
    const float v = (numT[bh * 4096 + u] + numT[524288 + bh * 4096 + u]) * den_lds[ag];
    G_lds[d * 72 + ag] = f2bf(v);
  }
  __syncthreads();

  const int nbase = nq * 256 + w * 64;
  const unsigned short* qp = qbf + (bh * 1024 + nbase) * 64;
  s16x8 qf[4][2];
#pragma unroll
  for (int mi = 0; mi < 4; ++mi)
#pragma unroll
    for (int kk = 0; kk < 2; ++kk)
      qf[mi][kk] = *(const s16x8*)(qp + (mi * 16 + lr) * 64 + kk * 32 + lg * 8);

  f32x4 L[4][4];
#pragma unroll
  for (int mi = 0; mi < 4; ++mi)
#pragma unroll
    for (int ni = 0; ni < 4; ++ni)
#pragma unroll
      for (int rr = 0; rr < 4; ++rr) L[mi][ni][rr] = 0.f;
#pragma unroll
  for (int kk = 0; kk < 2; ++kk)
#pragma unroll
    for (int ni = 0; ni < 4; ++ni) {
      const s16x8 bfr = *(const s16x8*)(A_lds + (ni * 16 + lr) * 72 + kk * 32 + lg * 8);
#pragma unroll
      for (int mi = 0; mi < 4; ++mi)
        L[mi][ni] = __builtin_amdgcn_mfma_f32_16x16x32_bf16(qf[mi][kk], bfr,
                                                            L[mi][ni], 0, 0, 0);
    }
  unsigned short* pw = P2_lds[w];
#pragma unroll
  for (int mi = 0; mi < 4; ++mi) {
    float ps[4][4];
    float rs[4];
#pragma unroll
    for (int rr = 0; rr < 4; ++rr) rs[rr] = 0.f;
#pragma unroll
    for (int ni = 0; ni < 4; ++ni) {
      const bool valid = (ni < 3) | (lr == 0);
#pragma unroll
      for (int rr = 0; rr < 4; ++rr) {
        const float p = valid ? __expf(L[mi][ni][rr] * 0.125f) : 0.f;
        ps[ni][rr] = p;
        rs[rr] += p;
      }
    }
#pragma unroll
    for (int rr = 0; rr < 4; ++rr) {
#pragma unroll
      for (int o = 1; o < 16; o <<= 1) rs[rr] += __shfl_xor(rs[rr], o, 64);
      rs[rr] = 1.f / rs[rr];
    }
#pragma unroll
    for (int ni = 0; ni < 4; ++ni)
#pragma unroll
      for (int rr = 0; rr < 4; ++rr)
        pw[(mi * 16 + lg * 4 + rr) * 72 + ni * 16 + lr] = f2bf(ps[ni][rr] * rs[rr]);
  }
#pragma unroll
  for (int mi = 0; mi < 4; ++mi) {
    f32x4 e[4];
#pragma unroll
    for (int ni = 0; ni < 4; ++ni)
#pragma unroll
      for (int rr = 0; rr < 4; ++rr) e[ni][rr] = 0.f;
#pragma unroll
    for (int kk = 0; kk < 2; ++kk) {
      const s16x8 pa = *(const s16x8*)(pw + (mi * 16 + lr) * 72 + kk * 32 + lg * 8);
#pragma unroll
      for (int ni = 0; ni < 4; ++ni) {
        const s16x8 gb = *(const s16x8*)(G_lds + (ni * 16 + lr) * 72 + kk * 32 + lg * 8);
        e[ni] = __builtin_amdgcn_mfma_f32_16x16x32_bf16(pa, gb, e[ni], 0, 0, 0);
      }
    }
#pragma unroll
    for (int ni = 0; ni < 4; ++ni)
#pragma unroll
      for (int rr = 0; rr < 4; ++rr) {
        const int n = nbase + mi * 16 + lg * 4 + rr;
        enh[(b * 1024 + n) * 512 + h * 64 + ni * 16 + lr] = f2bf(e[ni][rr]);
      }
  }
}

extern "C" void kernel_launch(void* const* d_in, const int* in_sizes, int n_in,
                              void* d_out, int out_size, void* d_ws, size_t ws_size,
                              hipStream_t stream) {
  const float* x    = (const float*)d_in[0];
  const float* q_w  = (const float*)d_in[3];
  const float* kv_w = (const float*)d_in[4];
  const float* dw_w = (const float*)d_in[5];
  const float* dw_b = (const float*)d_in[6];
  const float* bn_g = (const float*)d_in[7];
  const float* bn_b = (const float*)d_in[8];
  const float* bn_m = (const float*)d_in[9];
  const float* bn_v = (const float*)d_in[10];
  const float* pw_w = (const float*)d_in[11];
  const float* pw_b = (const float*)d_in[12];
  const float* pj_w = (const float*)d_in[13];
  const float* pj_b = (const float*)d_in[14];
  const float* e1_w = (const float*)d_in[15];
  const float* e1_b = (const float*)d_in[16];
  const float* e2_w = (const float*)d_in[17];
  const float* e2_b = (const float*)d_in[18];

  char* base = (char*)d_ws;
  size_t off = 0;
  auto alloc = [&](size_t bytes) -> void* {
    void* r = base + off;
    off += (bytes + 255) & ~(size_t)255;
    return r;
  };
  unsigned short* Wqkv = (unsigned short*)alloc(786432ull * 2);
  unsigned short* Wpj  = (unsigned short*)alloc(262144ull * 2);
  unsigned short* W1   = (unsigned short*)alloc(262144ull * 2);
  unsigned short* W2   = (unsigned short*)alloc(262144ull * 2);
  unsigned short* xT   = (unsigned short*)alloc(8388608ull * 2);
  unsigned short* qb   = (unsigned short*)alloc(8388608ull * 2);
  unsigned short* kb   = (unsigned short*)alloc(8388608ull * 2);
  unsigned short* vb   = (unsigned short*)alloc(8388608ull * 2);
  float* pbuf = (float*)alloc(401408ull * 4);
  float* rbuf = (float*)alloc(401408ull * 4);
  float* Abuf = (float*)alloc(401408ull * 4);
  float* numT = (float*)alloc(1048576ull * 4);
  float* denG = (float*)alloc(16384ull * 4);
  unsigned short* enh  = (unsigned short*)alloc(8388608ull * 2);
  float* xout = (float*)alloc(8388608ull * 4);
  unsigned short* xoutb = (unsigned short*)alloc(8388608ull * 2);
  unsigned short* h1    = (unsigned short*)alloc(8388608ull * 2);
  (void)ws_size; (void)in_sizes; (void)n_in; (void)out_size;

  k_weights<<<1536, 256, 0, stream>>>(q_w, kv_w, pj_w, e1_w, e2_w, Wqkv, Wpj, W1, W2);
  k_transpose<<<dim3(16, 8, 16), 256, 0, stream>>>(x, xT);
  k_pool<<<8192, 64, 0, stream>>>(x, pbuf);
  k_dw<<<8192, 64, 0, stream>>>(pbuf, dw_w, dw_b, bn_g, bn_b, bn_m, bn_v, rbuf);
  k_pw<<<256, 256, 0, stream>>>(rbuf, pw_w, pw_b, Abuf);
  k_gemm<0><<<1536, 256, 0, stream>>>(xT, Wqkv, qb, kb, vb,
                                      nullptr, nullptr, nullptr, nullptr, nullptr);
  k_aflash<<<256, 256, 0, stream>>>(Abuf, kb, vb, numT, denG);
  k_attn2<<<512, 256, 0, stream>>>(Abuf, numT, denG, qb, enh);
  k_gemm<1><<<512, 256, 0, stream>>>(enh, Wpj, nullptr, nullptr, nullptr,
                                     xout, xoutb, pj_b, nullptr, nullptr);
  k_gemm<2><<<512, 256, 0, stream>>>(xoutb, W1, nullptr, nullptr, nullptr,
                                     nullptr, h1, e1_b, nullptr, nullptr);
  k_gemm<3><<<512, 256, 0, stream>>>(h1, W2, nullptr, nullptr, nullptr,
                                     nullptr, nullptr, e2_b, xout, (float*)d_out);
}